// Round 1
// baseline (1630.340 us; speedup 1.0000x reference)
//
#include <hip/hip_runtime.h>
#include <cmath>

namespace {

constexpr int S = 2048, B = 2, D = 1024, H = 16, E = 64;
constexpr int RM = S * B;            // 4096 rows for the projection GEMMs
constexpr float MASKV = 1e18f;

// ---------------------------------------------------------------------------
// C[r,n] = sum_d A[r,d] * W[n,d] + bias[n]   (A:[RM,D] row-major, W:[N,D] row-major)
// MODE 0: C row-major [RM, D] (final output projection)
// MODE 1: scatter to per-head layout q_ws[((h*B+m)*S + i)*E + e], r=i*B+m, n=h*E+e
// ---------------------------------------------------------------------------
template<int MODE>
__global__ __launch_bounds__(256)
void gemm_nt(const float* __restrict__ A, const float* __restrict__ W,
             const float* __restrict__ bias, float* __restrict__ C)
{
    __shared__ float As[64][33];
    __shared__ float Ws[64][33];
    const int t  = threadIdx.x;
    const int tx = t & 15, ty = t >> 4;
    const int r0 = blockIdx.x * 64, n0 = blockIdx.y * 64;
    const int lrow = t >> 2;            // 0..63
    const int lc   = (t & 3) * 4;       // 0,4,8,12

    float acc[4][4] = {};

    for (int kt = 0; kt < D; kt += 32) {
        // stage 64x32 tiles of A and W
        float4 a0 = *reinterpret_cast<const float4*>(&A[(size_t)(r0 + lrow) * D + kt + lc]);
        float4 a1 = *reinterpret_cast<const float4*>(&A[(size_t)(r0 + lrow) * D + kt + 16 + lc]);
        float4 w0 = *reinterpret_cast<const float4*>(&W[(size_t)(n0 + lrow) * D + kt + lc]);
        float4 w1 = *reinterpret_cast<const float4*>(&W[(size_t)(n0 + lrow) * D + kt + 16 + lc]);
        As[lrow][lc+0]  = a0.x; As[lrow][lc+1]  = a0.y; As[lrow][lc+2]  = a0.z; As[lrow][lc+3]  = a0.w;
        As[lrow][lc+16] = a1.x; As[lrow][lc+17] = a1.y; As[lrow][lc+18] = a1.z; As[lrow][lc+19] = a1.w;
        Ws[lrow][lc+0]  = w0.x; Ws[lrow][lc+1]  = w0.y; Ws[lrow][lc+2]  = w0.z; Ws[lrow][lc+3]  = w0.w;
        Ws[lrow][lc+16] = w1.x; Ws[lrow][lc+17] = w1.y; Ws[lrow][lc+18] = w1.z; Ws[lrow][lc+19] = w1.w;
        __syncthreads();
        #pragma unroll 8
        for (int kk = 0; kk < 32; ++kk) {
            float a[4], b[4];
            #pragma unroll
            for (int u = 0; u < 4; ++u)  a[u] = As[ty*4 + u][kk];
            #pragma unroll
            for (int vv = 0; vv < 4; ++vv) b[vv] = Ws[tx*4 + vv][kk];
            #pragma unroll
            for (int u = 0; u < 4; ++u)
                #pragma unroll
                for (int vv = 0; vv < 4; ++vv)
                    acc[u][vv] = fmaf(a[u], b[vv], acc[u][vv]);
        }
        __syncthreads();
    }

    #pragma unroll
    for (int u = 0; u < 4; ++u) {
        const int r = r0 + ty*4 + u;
        #pragma unroll
        for (int vv = 0; vv < 4; ++vv) {
            const int n = n0 + tx*4 + vv;
            const float val = acc[u][vv] + bias[n];
            if (MODE == 0) {
                C[(size_t)r * D + n] = val;
            } else {
                const int i = r >> 1, m = r & 1, h = n >> 6, e = n & 63;
                C[(((size_t)(h * B + m)) * S + i) * E + e] = val;
            }
        }
    }
}

// ---------------------------------------------------------------------------
// Attention: per (h, m, 32-row q-tile), iterate over ALL 2048 keys in 32-tiles
// (full iteration required: fp32 mask semantics can mix future positions when
// an entire causal prefix is key-masked — scores tie at exactly -1e18f).
// Thread map: t -> row r = t>>3 (0..31), col-group cg = t&7.
//   scores: lane owns s[j = cg*4 .. cg*4+3]; online softmax reduced over the
//   8 lanes of a row with __shfl_xor width 8.
//   PV: lane owns O[r][cg*8 .. cg*8+7].
// ---------------------------------------------------------------------------
__global__ __launch_bounds__(256)
void attn_kernel(const float* __restrict__ q, const float* __restrict__ k,
                 const float* __restrict__ v, const int* __restrict__ key_mask,
                 float* __restrict__ attn_out)
{
    const int it = blockIdx.x;      // q-tile index, 0..63
    const int m  = blockIdx.y;      // batch
    const int h  = blockIdx.z;      // head
    const int i0 = it * 32;

    const float* Qb = q + (size_t)(h * B + m) * S * E;
    const float* Kb = k + (size_t)(h * B + m) * S * E;
    const float* Vb = v + (size_t)(h * B + m) * S * E;

    __shared__ float Qs[32][68];
    __shared__ float Ks[32][68];
    __shared__ float Vs[32][68];
    __shared__ float Ps[32][36];

    const int t  = threadIdx.x;
    const int r  = t >> 3;          // 0..31
    const int cg = t & 7;           // 0..7
    const int gi = i0 + r;          // global query row

    // stage Q tile (32x64): 8 floats per thread, float4 LDS stores (row stride 68 floats = 272B, 16B-aligned)
    {
        const int qc = cg * 8;
        const float* Qp = &Qb[(size_t)(i0 + r) * E + qc];
        *reinterpret_cast<float4*>(&Qs[r][qc])     = *reinterpret_cast<const float4*>(Qp);
        *reinterpret_cast<float4*>(&Qs[r][qc + 4]) = *reinterpret_cast<const float4*>(Qp + 4);
    }

    float m_run = -INFINITY, l_run = 0.0f;
    float o[8] = {0.f,0.f,0.f,0.f,0.f,0.f,0.f,0.f};

    for (int j0 = 0; j0 < S; j0 += 32) {
        __syncthreads();   // protect Ks/Vs/Ps from previous iteration's readers
        {
            const int kc = cg * 8;
            const float* Kp = &Kb[(size_t)(j0 + r) * E + kc];
            const float* Vp = &Vb[(size_t)(j0 + r) * E + kc];
            *reinterpret_cast<float4*>(&Ks[r][kc])     = *reinterpret_cast<const float4*>(Kp);
            *reinterpret_cast<float4*>(&Ks[r][kc + 4]) = *reinterpret_cast<const float4*>(Kp + 4);
            *reinterpret_cast<float4*>(&Vs[r][kc])     = *reinterpret_cast<const float4*>(Vp);
            *reinterpret_cast<float4*>(&Vs[r][kc + 4]) = *reinterpret_cast<const float4*>(Vp + 4);
        }
        __syncthreads();

        // ---- scores: s[jj] = Q[r] . K[cg*4+jj]
        float s[4] = {0.f, 0.f, 0.f, 0.f};
        #pragma unroll
        for (int e4 = 0; e4 < E; e4 += 4) {
            const float4 qv = *reinterpret_cast<const float4*>(&Qs[r][e4]);
            #pragma unroll
            for (int jj = 0; jj < 4; ++jj) {
                const float4 kv = *reinterpret_cast<const float4*>(&Ks[cg*4 + jj][e4]);
                s[jj] += qv.x*kv.x + qv.y*kv.y + qv.z*kv.z + qv.w*kv.w;
            }
        }

        // ---- mask + scale, exactly as reference (fp32, two separate subtractions)
        float mloc = -INFINITY;
        #pragma unroll
        for (int jj = 0; jj < 4; ++jj) {
            const int j = j0 + cg*4 + jj;
            float sc = s[jj] * 0.125f;                      // / sqrt(64)
            sc -= (key_mask[(size_t)j * B + m] != 0) ? MASKV : 0.0f;
            sc -= (j > gi) ? MASKV : 0.0f;
            s[jj] = sc;
            mloc = fmaxf(mloc, sc);
        }
        // row max over the 8 lanes of this row
        mloc = fmaxf(mloc, __shfl_xor(mloc, 1, 8));
        mloc = fmaxf(mloc, __shfl_xor(mloc, 2, 8));
        mloc = fmaxf(mloc, __shfl_xor(mloc, 4, 8));

        const float m_new = fmaxf(m_run, mloc);
        const float scale = expf(m_run - m_new);            // 0 when m_run=-inf
        float psum = 0.0f;
        #pragma unroll
        for (int jj = 0; jj < 4; ++jj) {
            const float p = expf(s[jj] - m_new);            // exp(-1e18)->0, exp(0)->1
            psum += p;
            Ps[r][cg*4 + jj] = p;
        }
        psum += __shfl_xor(psum, 1, 8);
        psum += __shfl_xor(psum, 2, 8);
        psum += __shfl_xor(psum, 4, 8);
        l_run = l_run * scale + psum;
        m_run = m_new;
        #pragma unroll
        for (int c = 0; c < 8; ++c) o[c] *= scale;

        __syncthreads();   // Ps visible (also orders vs. staging above)

        // ---- PV: O[r][cg*8 .. +7] += sum_j P[r][j] * V[j][...]
        const int co = cg * 8;
        #pragma unroll
        for (int j4 = 0; j4 < 32; j4 += 4) {
            const float4 pv = *reinterpret_cast<const float4*>(&Ps[r][j4]);
            const float pj[4] = {pv.x, pv.y, pv.z, pv.w};
            #pragma unroll
            for (int jj = 0; jj < 4; ++jj) {
                const float4 va = *reinterpret_cast<const float4*>(&Vs[j4 + jj][co]);
                const float4 vb = *reinterpret_cast<const float4*>(&Vs[j4 + jj][co + 4]);
                o[0] = fmaf(pj[jj], va.x, o[0]);
                o[1] = fmaf(pj[jj], va.y, o[1]);
                o[2] = fmaf(pj[jj], va.z, o[2]);
                o[3] = fmaf(pj[jj], va.w, o[3]);
                o[4] = fmaf(pj[jj], vb.x, o[4]);
                o[5] = fmaf(pj[jj], vb.y, o[5]);
                o[6] = fmaf(pj[jj], vb.z, o[6]);
                o[7] = fmaf(pj[jj], vb.w, o[7]);
            }
        }
    }

    // epilogue: normalize and write attn_out[(i,m), h*64 + cg*8 ..]
    const float inv = 1.0f / l_run;
    float* dst = attn_out + ((size_t)gi * B + m) * D + h * E + cg * 8;
    float4 oa, ob;
    oa.x = o[0]*inv; oa.y = o[1]*inv; oa.z = o[2]*inv; oa.w = o[3]*inv;
    ob.x = o[4]*inv; ob.y = o[5]*inv; ob.z = o[6]*inv; ob.w = o[7]*inv;
    *reinterpret_cast<float4*>(dst)     = oa;
    *reinterpret_cast<float4*>(dst + 4) = ob;
}

} // anonymous namespace

extern "C" void kernel_launch(void* const* d_in, const int* in_sizes, int n_in,
                              void* d_out, int out_size, void* d_ws, size_t ws_size,
                              hipStream_t stream)
{
    const float* query = (const float*)d_in[0];
    const float* key   = (const float*)d_in[1];
    const float* value = (const float*)d_in[2];
    const int*   kmask = (const int*)  d_in[3];
    const float* Wq    = (const float*)d_in[4];
    const float* bq    = (const float*)d_in[5];
    const float* Wk    = (const float*)d_in[6];
    const float* bk    = (const float*)d_in[7];
    const float* Wv    = (const float*)d_in[8];
    const float* bv    = (const float*)d_in[9];
    const float* Wo    = (const float*)d_in[10];
    const float* bo    = (const float*)d_in[11];
    float* out = (float*)d_out;

    const size_t headbuf = (size_t)H * B * S * E;   // 4,194,304 floats
    float* q_ws = (float*)d_ws;
    float* k_ws = q_ws + headbuf;
    float* v_ws = k_ws + headbuf;
    float* a_ws = v_ws + headbuf;                   // [RM, D]

    const dim3 gg(RM / 64, D / 64);
    gemm_nt<1><<<gg, 256, 0, stream>>>(query, Wq, bq, q_ws);
    gemm_nt<1><<<gg, 256, 0, stream>>>(key,   Wk, bk, k_ws);
    gemm_nt<1><<<gg, 256, 0, stream>>>(value, Wv, bv, v_ws);

    attn_kernel<<<dim3(S / 32, B, H), 256, 0, stream>>>(q_ws, k_ws, v_ws, kmask, a_ws);

    gemm_nt<0><<<gg, 256, 0, stream>>>(a_ws, Wo, bo, out);
}

// Round 2
// 806.775 us; speedup vs baseline: 2.0208x; 2.0208x over previous
//
#include <hip/hip_runtime.h>
#include <cmath>

namespace {

constexpr int S = 2048, B = 2, D = 1024, H = 16, E = 64;
constexpr int RM = S * B;
constexpr float MASKV = 1e18f;
constexpr int QBLK = 64, KVB = 64;

using s16x8 = __attribute__((ext_vector_type(8))) short;
using f32x4 = __attribute__((ext_vector_type(4))) float;

__device__ inline f32x4 mfma16(s16x8 a, s16x8 b, f32x4 c) {
    return __builtin_amdgcn_mfma_f32_16x16x32_bf16(a, b, c, 0, 0, 0);
}

__device__ inline unsigned short f2bf(float f) {
    unsigned u = __builtin_bit_cast(unsigned, f);
    u += 0x7fffu + ((u >> 16) & 1u);          // RNE
    return (unsigned short)(u >> 16);
}

// ---------------------------------------------------------------------------
// C[r,n] = sum_d A[r,d] * W[n,d] + bias[n]
// MODE 0: fp32 row-major [RM, D]
// MODE 1: bf16 scatter  [((h*B+m)*S + i)*E + e]      (q, k)
// MODE 2: bf16 scatter transposed [((h*B+m)*E + e)*S + i]   (v^T)
// ---------------------------------------------------------------------------
template<int MODE>
__global__ __launch_bounds__(256)
void gemm_nt(const float* __restrict__ A, const float* __restrict__ W,
             const float* __restrict__ bias, void* __restrict__ Cout)
{
    __shared__ float As[64][33];
    __shared__ float Ws[64][33];
    const int t  = threadIdx.x;
    const int tx = t & 15, ty = t >> 4;
    const int r0 = blockIdx.x * 64, n0 = blockIdx.y * 64;
    const int lrow = t >> 2;
    const int lc   = (t & 3) * 4;

    float acc[4][4] = {};

    for (int kt = 0; kt < D; kt += 32) {
        float4 a0 = *reinterpret_cast<const float4*>(&A[(size_t)(r0 + lrow) * D + kt + lc]);
        float4 a1 = *reinterpret_cast<const float4*>(&A[(size_t)(r0 + lrow) * D + kt + 16 + lc]);
        float4 w0 = *reinterpret_cast<const float4*>(&W[(size_t)(n0 + lrow) * D + kt + lc]);
        float4 w1 = *reinterpret_cast<const float4*>(&W[(size_t)(n0 + lrow) * D + kt + 16 + lc]);
        As[lrow][lc+0]  = a0.x; As[lrow][lc+1]  = a0.y; As[lrow][lc+2]  = a0.z; As[lrow][lc+3]  = a0.w;
        As[lrow][lc+16] = a1.x; As[lrow][lc+17] = a1.y; As[lrow][lc+18] = a1.z; As[lrow][lc+19] = a1.w;
        Ws[lrow][lc+0]  = w0.x; Ws[lrow][lc+1]  = w0.y; Ws[lrow][lc+2]  = w0.z; Ws[lrow][lc+3]  = w0.w;
        Ws[lrow][lc+16] = w1.x; Ws[lrow][lc+17] = w1.y; Ws[lrow][lc+18] = w1.z; Ws[lrow][lc+19] = w1.w;
        __syncthreads();
        #pragma unroll 8
        for (int kk = 0; kk < 32; ++kk) {
            float a[4], b[4];
            #pragma unroll
            for (int u = 0; u < 4; ++u)  a[u] = As[ty*4 + u][kk];
            #pragma unroll
            for (int vv = 0; vv < 4; ++vv) b[vv] = Ws[tx*4 + vv][kk];
            #pragma unroll
            for (int u = 0; u < 4; ++u)
                #pragma unroll
                for (int vv = 0; vv < 4; ++vv)
                    acc[u][vv] = fmaf(a[u], b[vv], acc[u][vv]);
        }
        __syncthreads();
    }

    #pragma unroll
    for (int u = 0; u < 4; ++u) {
        const int r = r0 + ty*4 + u;
        #pragma unroll
        for (int vv = 0; vv < 4; ++vv) {
            const int n = n0 + tx*4 + vv;
            const float val = acc[u][vv] + bias[n];
            if (MODE == 0) {
                ((float*)Cout)[(size_t)r * D + n] = val;
            } else {
                const int i = r >> 1, m = r & 1, h = n >> 6, e = n & 63;
                if (MODE == 1)
                    ((unsigned short*)Cout)[(((size_t)(h * B + m)) * S + i) * E + e] = f2bf(val);
                else
                    ((unsigned short*)Cout)[(((size_t)(h * B + m)) * E + e) * S + i] = f2bf(val);
            }
        }
    }
}

// ---------------------------------------------------------------------------
// MFMA flash attention. Block: 4 waves, QBLK=64 q-rows of one (h,m); each wave
// owns 16 q-rows. KV tiles of 64. Full-S iteration unless an unmasked key
// exists in [0, i0) (then causal skip is exact: exp(-1e18)=0).
// Fragment maps (16x16x32 bf16): A row=l&15, k=(l>>4)*8+i (8 contig);
// B col=l&15, k=(l>>4)*8+i (8 contig); C/D col=l&15, row=(l>>4)*4+reg.
// ---------------------------------------------------------------------------
__global__ __launch_bounds__(256)
void attn_mfma(const unsigned short* __restrict__ q,
               const unsigned short* __restrict__ k,
               const unsigned short* __restrict__ vt,
               const int* __restrict__ key_mask,
               float* __restrict__ attn_out)
{
    const int it = blockIdx.x, m = blockIdx.y, h = blockIdx.z;
    const int i0 = it * QBLK;
    const int hm = h * B + m;
    const unsigned short* Qb  = q  + (size_t)hm * S * E;
    const unsigned short* Kb  = k  + (size_t)hm * S * E;
    const unsigned short* Vtb = vt + (size_t)hm * E * S;

    __shared__ unsigned short Ks[KVB][72];     // [key][e], stride 144B
    __shared__ unsigned short Vts[E][72];      // [e][key]
    __shared__ unsigned short Pw[4][16][72];   // per-wave P: [qrow][key]
    __shared__ float kms[KVB];
    __shared__ int sflag;

    const int t  = threadIdx.x;
    const int wv = t >> 6;
    const int l  = t & 63;
    const int lg = l >> 4;     // 0..3
    const int lcc = l & 15;    // 0..15

    if (t == 0) sflag = 0;
    __syncthreads();
    {
        bool any = false;
        for (int j = t; j < i0; j += 256) any |= (key_mask[(size_t)j * B + m] == 0);
        if (any) sflag = 1;
    }
    __syncthreads();
    const int jend = sflag ? (i0 + QBLK) : S;

    // Q fragments (A operand): row = wave's q-row (l&15), k = e chunks
    s16x8 qf0, qf1;
    {
        const unsigned short* qp = &Qb[(size_t)(i0 + wv * 16 + lcc) * E + lg * 8];
        qf0 = *reinterpret_cast<const s16x8*>(qp);
        qf1 = *reinterpret_cast<const s16x8*>(qp + 32);
    }

    float m_run[4] = {-INFINITY, -INFINITY, -INFINITY, -INFINITY};
    float l_run[4] = {0.f, 0.f, 0.f, 0.f};
    f32x4 oacc[4] = {};

    const int ch = (t & 7) * 8, rw = t >> 3;   // staging map

    for (int j0 = 0; j0 < jend; j0 += KVB) {
        __syncthreads();
        *reinterpret_cast<s16x8*>(&Ks[rw][ch])      = *reinterpret_cast<const s16x8*>(&Kb[(size_t)(j0 + rw) * E + ch]);
        *reinterpret_cast<s16x8*>(&Ks[rw + 32][ch]) = *reinterpret_cast<const s16x8*>(&Kb[(size_t)(j0 + rw + 32) * E + ch]);
        *reinterpret_cast<s16x8*>(&Vts[rw][ch])      = *reinterpret_cast<const s16x8*>(&Vtb[(size_t)rw * S + j0 + ch]);
        *reinterpret_cast<s16x8*>(&Vts[rw + 32][ch]) = *reinterpret_cast<const s16x8*>(&Vtb[(size_t)(rw + 32) * S + j0 + ch]);
        if (t < KVB) kms[t] = key_mask[(size_t)(j0 + t) * B + m] ? MASKV : 0.0f;
        __syncthreads();

        // ---- QK^T: 4 key-groups x (2 mfma over e)
        f32x4 sacc[4];
        #pragma unroll
        for (int jt = 0; jt < 4; ++jt) {
            s16x8 kf0 = *reinterpret_cast<const s16x8*>(&Ks[jt * 16 + lcc][lg * 8]);
            s16x8 kf1 = *reinterpret_cast<const s16x8*>(&Ks[jt * 16 + lcc][32 + lg * 8]);
            f32x4 a = {};
            a = mfma16(qf0, kf0, a);
            a = mfma16(qf1, kf1, a);
            sacc[jt] = a;
        }

        // ---- mask + scale (bit-exact fp32 semantics)
        #pragma unroll
        for (int jt = 0; jt < 4; ++jt) {
            const int j = j0 + jt * 16 + lcc;
            const float km = kms[jt * 16 + lcc];
            #pragma unroll
            for (int r = 0; r < 4; ++r) {
                const int gi = i0 + wv * 16 + lg * 4 + r;
                float sc = sacc[jt][r] * 0.125f;
                sc -= km;
                sc -= (j > gi) ? MASKV : 0.0f;
                sacc[jt][r] = sc;
            }
        }

        // ---- online softmax (rows live in 16-lane groups)
        float mloc[4], scale[4], psum[4];
        #pragma unroll
        for (int r = 0; r < 4; ++r) {
            float mm = fmaxf(fmaxf(sacc[0][r], sacc[1][r]), fmaxf(sacc[2][r], sacc[3][r]));
            mm = fmaxf(mm, __shfl_xor(mm, 1, 16));
            mm = fmaxf(mm, __shfl_xor(mm, 2, 16));
            mm = fmaxf(mm, __shfl_xor(mm, 4, 16));
            mm = fmaxf(mm, __shfl_xor(mm, 8, 16));
            mloc[r] = mm;
            const float m_new = fmaxf(m_run[r], mm);
            scale[r] = __expf(m_run[r] - m_new);
            m_run[r] = m_new;
            psum[r] = 0.f;
        }
        #pragma unroll
        for (int jt = 0; jt < 4; ++jt) {
            #pragma unroll
            for (int r = 0; r < 4; ++r) {
                const float p = __expf(sacc[jt][r] - m_run[r]);
                psum[r] += p;
                Pw[wv][lg * 4 + r][jt * 16 + lcc] = f2bf(p);
            }
        }
        #pragma unroll
        for (int r = 0; r < 4; ++r) {
            float ps = psum[r];
            ps += __shfl_xor(ps, 1, 16);
            ps += __shfl_xor(ps, 2, 16);
            ps += __shfl_xor(ps, 4, 16);
            ps += __shfl_xor(ps, 8, 16);
            l_run[r] = l_run[r] * scale[r] + ps;
            oacc[0][r] *= scale[r];
            oacc[1][r] *= scale[r];
            oacc[2][r] *= scale[r];
            oacc[3][r] *= scale[r];
        }

        // ---- PV: A = P (per-wave LDS), B = V^T tiles
        s16x8 pf0 = *reinterpret_cast<const s16x8*>(&Pw[wv][lcc][lg * 8]);
        s16x8 pf1 = *reinterpret_cast<const s16x8*>(&Pw[wv][lcc][32 + lg * 8]);
        #pragma unroll
        for (int et = 0; et < 4; ++et) {
            s16x8 vf0 = *reinterpret_cast<const s16x8*>(&Vts[et * 16 + lcc][lg * 8]);
            s16x8 vf1 = *reinterpret_cast<const s16x8*>(&Vts[et * 16 + lcc][32 + lg * 8]);
            oacc[et] = mfma16(pf0, vf0, oacc[et]);
            oacc[et] = mfma16(pf1, vf1, oacc[et]);
        }
    }

    // ---- epilogue
    #pragma unroll
    for (int r = 0; r < 4; ++r) {
        const float inv = 1.0f / l_run[r];
        const int gi = i0 + wv * 16 + lg * 4 + r;
        float* dst = attn_out + ((size_t)gi * B + m) * D + h * E;
        #pragma unroll
        for (int et = 0; et < 4; ++et)
            dst[et * 16 + lcc] = oacc[et][r] * inv;
    }
}

} // anonymous namespace

extern "C" void kernel_launch(void* const* d_in, const int* in_sizes, int n_in,
                              void* d_out, int out_size, void* d_ws, size_t ws_size,
                              hipStream_t stream)
{
    const float* query = (const float*)d_in[0];
    const float* key   = (const float*)d_in[1];
    const float* value = (const float*)d_in[2];
    const int*   kmask = (const int*)  d_in[3];
    const float* Wq    = (const float*)d_in[4];
    const float* bq    = (const float*)d_in[5];
    const float* Wk    = (const float*)d_in[6];
    const float* bk    = (const float*)d_in[7];
    const float* Wv    = (const float*)d_in[8];
    const float* bv    = (const float*)d_in[9];
    const float* Wo    = (const float*)d_in[10];
    const float* bo    = (const float*)d_in[11];
    float* out = (float*)d_out;

    const size_t headbuf = (size_t)H * B * S * E;            // 4,194,304 elems
    unsigned short* q_ws  = (unsigned short*)d_ws;           // bf16, 8 MB
    unsigned short* k_ws  = q_ws + headbuf;                  // bf16, 8 MB
    unsigned short* vt_ws = k_ws + headbuf;                  // bf16 (transposed), 8 MB
    float*          a_ws  = (float*)(vt_ws + headbuf);       // fp32 [RM, D], 16 MB

    const dim3 gg(RM / 64, D / 64);
    gemm_nt<1><<<gg, 256, 0, stream>>>(query, Wq, bq, q_ws);
    gemm_nt<1><<<gg, 256, 0, stream>>>(key,   Wk, bk, k_ws);
    gemm_nt<2><<<gg, 256, 0, stream>>>(value, Wv, bv, vt_ws);

    attn_mfma<<<dim3(S / QBLK, B, H), 256, 0, stream>>>(q_ws, k_ws, vt_ws, kmask, a_ws);

    gemm_nt<0><<<gg, 256, 0, stream>>>(a_ws, Wo, bo, out);
}

// Round 3
// 200.118 us; speedup vs baseline: 8.1469x; 4.0315x over previous
//
#include <hip/hip_runtime.h>
#include <cmath>

namespace {

constexpr int S = 2048, B = 2, D = 1024, H = 16, E = 64;
constexpr int RM = S * B;        // 4096 GEMM rows
constexpr int K = D;             // GEMM inner dim
constexpr float MASKV = 1e18f;
constexpr int QBLK = 64, KVB = 64;

using s16x8 = __attribute__((ext_vector_type(8))) short;
using u16x8 = __attribute__((ext_vector_type(8))) unsigned short;
using f32x4 = __attribute__((ext_vector_type(4))) float;
typedef unsigned short ushort;
typedef unsigned int u32;

__device__ inline f32x4 mfma16(s16x8 a, s16x8 b, f32x4 c) {
    return __builtin_amdgcn_mfma_f32_16x16x32_bf16(a, b, c, 0, 0, 0);
}

__device__ inline ushort f2bf(float f) {
    unsigned u = __builtin_bit_cast(unsigned, f);
    u += 0x7fffu + ((u >> 16) & 1u);          // RNE
    return (ushort)(u >> 16);
}

__device__ inline void gload_lds16(const void* g, void* l) {
    __builtin_amdgcn_global_load_lds(
        (const __attribute__((address_space(1))) u32*)g,
        (__attribute__((address_space(3))) u32*)l,
        16, 0, 0);
}

// ---------------------------------------------------------------------------
// fp32 -> bf16 converters (memory-bound, vectorized 8 elem/thread)
// ---------------------------------------------------------------------------
__global__ __launch_bounds__(256)
void cvt3_kernel(const float* __restrict__ a, const float* __restrict__ b,
                 const float* __restrict__ c,
                 ushort* __restrict__ ao, ushort* __restrict__ bo2, ushort* __restrict__ co)
{
    const float* src = (blockIdx.y == 0) ? a : (blockIdx.y == 1) ? b : c;
    ushort* dst      = (blockIdx.y == 0) ? ao : (blockIdx.y == 1) ? bo2 : co;
    const size_t i = ((size_t)blockIdx.x * 256 + threadIdx.x) * 8;
    float4 x = *reinterpret_cast<const float4*>(&src[i]);
    float4 y = *reinterpret_cast<const float4*>(&src[i + 4]);
    u16x8 o;
    o[0]=f2bf(x.x); o[1]=f2bf(x.y); o[2]=f2bf(x.z); o[3]=f2bf(x.w);
    o[4]=f2bf(y.x); o[5]=f2bf(y.y); o[6]=f2bf(y.z); o[7]=f2bf(y.w);
    *reinterpret_cast<u16x8*>(&dst[i]) = o;
}

__global__ __launch_bounds__(256)
void cvt4_kernel(const float* __restrict__ a, const float* __restrict__ b,
                 const float* __restrict__ c, const float* __restrict__ d,
                 ushort* __restrict__ ao, ushort* __restrict__ bo2,
                 ushort* __restrict__ co, ushort* __restrict__ dd)
{
    const float* src = (blockIdx.y == 0) ? a : (blockIdx.y == 1) ? b : (blockIdx.y == 2) ? c : d;
    ushort* dst      = (blockIdx.y == 0) ? ao : (blockIdx.y == 1) ? bo2 : (blockIdx.y == 2) ? co : dd;
    const size_t i = ((size_t)blockIdx.x * 256 + threadIdx.x) * 8;
    float4 x = *reinterpret_cast<const float4*>(&src[i]);
    float4 y = *reinterpret_cast<const float4*>(&src[i + 4]);
    u16x8 o;
    o[0]=f2bf(x.x); o[1]=f2bf(x.y); o[2]=f2bf(x.z); o[3]=f2bf(x.w);
    o[4]=f2bf(y.x); o[5]=f2bf(y.y); o[6]=f2bf(y.z); o[7]=f2bf(y.w);
    *reinterpret_cast<u16x8*>(&dst[i]) = o;
}

// ---------------------------------------------------------------------------
// MFMA GEMM core: C[128,64] tile of A[RM,K] * W[N,K]^T, bf16 in, fp32 acc.
// global_load_lds direct staging, linear LDS dest + pre-swizzled global source
// (rule #21: source permutation == read permutation, chunk ^= row&7).
// 4 waves, each 64x32 (4x2 fragments of 16x16x32).
// ---------------------------------------------------------------------------
__device__ inline void mm_core(const ushort* __restrict__ A, const ushort* __restrict__ W,
                               ushort* Albuf, ushort* Blbuf, int r0, int n0,
                               f32x4 (&acc)[4][2])
{
    const int t  = threadIdx.x;
    const int w  = t >> 6, l = t & 63;
    const int lr = l & 15, lg = l >> 4;
    const int wr = w >> 1, wc = w & 1;
    const int srow = t >> 3;              // staging row within 32-row group
    const int gch  = (t & 7) ^ (srow & 7);  // pre-swizzled source chunk

    for (int kt = 0; kt < K; kt += 64) {
        __syncthreads();
        #pragma unroll
        for (int c = 0; c < 4; ++c) {     // A: 128 rows x 64 bf16 = 16 KB
            const int row = c * 32 + srow;
            gload_lds16(&A[(size_t)(r0 + row) * K + kt + gch * 8],
                        (char*)Albuf + c * 4096 + t * 16);
        }
        #pragma unroll
        for (int c = 0; c < 2; ++c) {     // W: 64 rows x 64 bf16 = 8 KB
            const int row = c * 32 + srow;
            gload_lds16(&W[(size_t)(n0 + row) * K + kt + gch * 8],
                        (char*)Blbuf + c * 4096 + t * 16);
        }
        __syncthreads();                  // compiler drains vmcnt here

        #pragma unroll
        for (int ks = 0; ks < 2; ++ks) {
            s16x8 af[4], bf[2];
            #pragma unroll
            for (int mf = 0; mf < 4; ++mf) {
                const int row = wr * 64 + mf * 16 + lr;
                const int ch  = (ks * 4 + lg) ^ (row & 7);
                af[mf] = *reinterpret_cast<const s16x8*>((const char*)Albuf + row * 128 + ch * 16);
            }
            #pragma unroll
            for (int nf = 0; nf < 2; ++nf) {
                const int row = wc * 32 + nf * 16 + lr;
                const int ch  = (ks * 4 + lg) ^ (row & 7);
                bf[nf] = *reinterpret_cast<const s16x8*>((const char*)Blbuf + row * 128 + ch * 16);
            }
            #pragma unroll
            for (int mf = 0; mf < 4; ++mf)
                #pragma unroll
                for (int nf = 0; nf < 2; ++nf)
                    acc[mf][nf] = mfma16(af[mf], bf[nf], acc[mf][nf]);
        }
    }
}

// Fused QKV projections: blockIdx.z selects (A, W, bias, dst). z<2 -> head
// layout [((h*B+m)*S+i)*E+e]; z==2 -> transposed [((h*B+m)*E+e)*S+i].
__global__ __launch_bounds__(256)
void proj_gemm(const ushort* __restrict__ qa, const ushort* __restrict__ ka,
               const ushort* __restrict__ va,
               const ushort* __restrict__ wq, const ushort* __restrict__ wk,
               const ushort* __restrict__ wv,
               const float* __restrict__ bq, const float* __restrict__ bk,
               const float* __restrict__ bv,
               ushort* __restrict__ qd, ushort* __restrict__ kd, ushort* __restrict__ vtd)
{
    __shared__ ushort Albuf[128 * 64];
    __shared__ ushort Blbuf[64 * 64];
    const int z = blockIdx.z;
    const ushort* A    = (z == 0) ? qa : (z == 1) ? ka : va;
    const ushort* W    = (z == 0) ? wq : (z == 1) ? wk : wv;
    const float*  bias = (z == 0) ? bq : (z == 1) ? bk : bv;
    const int r0 = blockIdx.x * 128, n0 = blockIdx.y * 64;

    f32x4 acc[4][2] = {};
    mm_core(A, W, Albuf, Blbuf, r0, n0, acc);

    const int t = threadIdx.x, w = t >> 6, l = t & 63, lr = l & 15, lg = l >> 4;
    const int wr = w >> 1, wc = w & 1;
    #pragma unroll
    for (int mf = 0; mf < 4; ++mf) {
        #pragma unroll
        for (int nf = 0; nf < 2; ++nf) {
            const int n = n0 + wc * 32 + nf * 16 + lr;
            const int h = n >> 6, e = n & 63;
            const float bb = bias[n];
            #pragma unroll
            for (int rg = 0; rg < 4; ++rg) {
                const int r = r0 + wr * 64 + mf * 16 + lg * 4 + rg;
                const int i = r >> 1, m = r & 1;
                const ushort val = f2bf(acc[mf][nf][rg] + bb);
                if (z < 2) {
                    ushort* dst = (z == 0) ? qd : kd;
                    dst[(((size_t)(h * B + m)) * S + i) * E + e] = val;
                } else {
                    vtd[(((size_t)(h * B + m)) * E + e) * S + i] = val;
                }
            }
        }
    }
}

__global__ __launch_bounds__(256)
void out_gemm(const ushort* __restrict__ A, const ushort* __restrict__ W,
              const float* __restrict__ bias, float* __restrict__ Cout)
{
    __shared__ ushort Albuf[128 * 64];
    __shared__ ushort Blbuf[64 * 64];
    const int r0 = blockIdx.x * 128, n0 = blockIdx.y * 64;

    f32x4 acc[4][2] = {};
    mm_core(A, W, Albuf, Blbuf, r0, n0, acc);

    const int t = threadIdx.x, w = t >> 6, l = t & 63, lr = l & 15, lg = l >> 4;
    const int wr = w >> 1, wc = w & 1;
    #pragma unroll
    for (int mf = 0; mf < 4; ++mf) {
        #pragma unroll
        for (int nf = 0; nf < 2; ++nf) {
            const int n = n0 + wc * 32 + nf * 16 + lr;
            const float bb = bias[n];
            #pragma unroll
            for (int rg = 0; rg < 4; ++rg) {
                const int r = r0 + wr * 64 + mf * 16 + lg * 4 + rg;
                Cout[(size_t)r * D + n] = acc[mf][nf][rg] + bb;
            }
        }
    }
}

// ---------------------------------------------------------------------------
// MFMA flash attention (unchanged from R2 except bf16 output).
// ---------------------------------------------------------------------------
__global__ __launch_bounds__(256)
void attn_mfma(const ushort* __restrict__ q, const ushort* __restrict__ k,
               const ushort* __restrict__ vt, const int* __restrict__ key_mask,
               ushort* __restrict__ attn_out)
{
    const int it = blockIdx.x, m = blockIdx.y, h = blockIdx.z;
    const int i0 = it * QBLK;
    const int hm = h * B + m;
    const ushort* Qb  = q  + (size_t)hm * S * E;
    const ushort* Kb  = k  + (size_t)hm * S * E;
    const ushort* Vtb = vt + (size_t)hm * E * S;

    __shared__ ushort Ks[KVB][72];
    __shared__ ushort Vts[E][72];
    __shared__ ushort Pw[4][16][72];
    __shared__ float kms[KVB];
    __shared__ int sflag;

    const int t  = threadIdx.x;
    const int wv = t >> 6;
    const int l  = t & 63;
    const int lg = l >> 4;
    const int lcc = l & 15;

    if (t == 0) sflag = 0;
    __syncthreads();
    {
        bool any = false;
        for (int j = t; j < i0; j += 256) any |= (key_mask[(size_t)j * B + m] == 0);
        if (any) sflag = 1;
    }
    __syncthreads();
    const int jend = sflag ? (i0 + QBLK) : S;

    s16x8 qf0, qf1;
    {
        const ushort* qp = &Qb[(size_t)(i0 + wv * 16 + lcc) * E + lg * 8];
        qf0 = *reinterpret_cast<const s16x8*>(qp);
        qf1 = *reinterpret_cast<const s16x8*>(qp + 32);
    }

    float m_run[4] = {-INFINITY, -INFINITY, -INFINITY, -INFINITY};
    float l_run[4] = {0.f, 0.f, 0.f, 0.f};
    f32x4 oacc[4] = {};

    const int ch = (t & 7) * 8, rw = t >> 3;

    for (int j0 = 0; j0 < jend; j0 += KVB) {
        __syncthreads();
        *reinterpret_cast<s16x8*>(&Ks[rw][ch])      = *reinterpret_cast<const s16x8*>(&Kb[(size_t)(j0 + rw) * E + ch]);
        *reinterpret_cast<s16x8*>(&Ks[rw + 32][ch]) = *reinterpret_cast<const s16x8*>(&Kb[(size_t)(j0 + rw + 32) * E + ch]);
        *reinterpret_cast<s16x8*>(&Vts[rw][ch])      = *reinterpret_cast<const s16x8*>(&Vtb[(size_t)rw * S + j0 + ch]);
        *reinterpret_cast<s16x8*>(&Vts[rw + 32][ch]) = *reinterpret_cast<const s16x8*>(&Vtb[(size_t)(rw + 32) * S + j0 + ch]);
        if (t < KVB) kms[t] = key_mask[(size_t)(j0 + t) * B + m] ? MASKV : 0.0f;
        __syncthreads();

        f32x4 sacc[4];
        #pragma unroll
        for (int jt = 0; jt < 4; ++jt) {
            s16x8 kf0 = *reinterpret_cast<const s16x8*>(&Ks[jt * 16 + lcc][lg * 8]);
            s16x8 kf1 = *reinterpret_cast<const s16x8*>(&Ks[jt * 16 + lcc][32 + lg * 8]);
            f32x4 a = {};
            a = mfma16(qf0, kf0, a);
            a = mfma16(qf1, kf1, a);
            sacc[jt] = a;
        }

        #pragma unroll
        for (int jt = 0; jt < 4; ++jt) {
            const int j = j0 + jt * 16 + lcc;
            const float km = kms[jt * 16 + lcc];
            #pragma unroll
            for (int r = 0; r < 4; ++r) {
                const int gi = i0 + wv * 16 + lg * 4 + r;
                float sc = sacc[jt][r] * 0.125f;
                sc -= km;
                sc -= (j > gi) ? MASKV : 0.0f;
                sacc[jt][r] = sc;
            }
        }

        float scale[4], psum[4];
        #pragma unroll
        for (int r = 0; r < 4; ++r) {
            float mm = fmaxf(fmaxf(sacc[0][r], sacc[1][r]), fmaxf(sacc[2][r], sacc[3][r]));
            mm = fmaxf(mm, __shfl_xor(mm, 1, 16));
            mm = fmaxf(mm, __shfl_xor(mm, 2, 16));
            mm = fmaxf(mm, __shfl_xor(mm, 4, 16));
            mm = fmaxf(mm, __shfl_xor(mm, 8, 16));
            const float m_new = fmaxf(m_run[r], mm);
            scale[r] = __expf(m_run[r] - m_new);
            m_run[r] = m_new;
            psum[r] = 0.f;
        }
        #pragma unroll
        for (int jt = 0; jt < 4; ++jt) {
            #pragma unroll
            for (int r = 0; r < 4; ++r) {
                const float p = __expf(sacc[jt][r] - m_run[r]);
                psum[r] += p;
                Pw[wv][lg * 4 + r][jt * 16 + lcc] = f2bf(p);
            }
        }
        #pragma unroll
        for (int r = 0; r < 4; ++r) {
            float ps = psum[r];
            ps += __shfl_xor(ps, 1, 16);
            ps += __shfl_xor(ps, 2, 16);
            ps += __shfl_xor(ps, 4, 16);
            ps += __shfl_xor(ps, 8, 16);
            l_run[r] = l_run[r] * scale[r] + ps;
            oacc[0][r] *= scale[r];
            oacc[1][r] *= scale[r];
            oacc[2][r] *= scale[r];
            oacc[3][r] *= scale[r];
        }

        s16x8 pf0 = *reinterpret_cast<const s16x8*>(&Pw[wv][lcc][lg * 8]);
        s16x8 pf1 = *reinterpret_cast<const s16x8*>(&Pw[wv][lcc][32 + lg * 8]);
        #pragma unroll
        for (int et = 0; et < 4; ++et) {
            s16x8 vf0 = *reinterpret_cast<const s16x8*>(&Vts[et * 16 + lcc][lg * 8]);
            s16x8 vf1 = *reinterpret_cast<const s16x8*>(&Vts[et * 16 + lcc][32 + lg * 8]);
            oacc[et] = mfma16(pf0, vf0, oacc[et]);
            oacc[et] = mfma16(pf1, vf1, oacc[et]);
        }
    }

    #pragma unroll
    for (int r = 0; r < 4; ++r) {
        const float inv = 1.0f / l_run[r];
        const int gi = i0 + wv * 16 + lg * 4 + r;
        ushort* dst = attn_out + ((size_t)gi * B + m) * D + h * E;
        #pragma unroll
        for (int et = 0; et < 4; ++et)
            dst[et * 16 + lcc] = f2bf(oacc[et][r] * inv);
    }
}

} // anonymous namespace

extern "C" void kernel_launch(void* const* d_in, const int* in_sizes, int n_in,
                              void* d_out, int out_size, void* d_ws, size_t ws_size,
                              hipStream_t stream)
{
    const float* query = (const float*)d_in[0];
    const float* key   = (const float*)d_in[1];
    const float* value = (const float*)d_in[2];
    const int*   kmask = (const int*)  d_in[3];
    const float* Wq    = (const float*)d_in[4];
    const float* bq    = (const float*)d_in[5];
    const float* Wk    = (const float*)d_in[6];
    const float* bk    = (const float*)d_in[7];
    const float* Wv    = (const float*)d_in[8];
    const float* bv    = (const float*)d_in[9];
    const float* Wo    = (const float*)d_in[10];
    const float* bo    = (const float*)d_in[11];
    float* out = (float*)d_out;

    const size_t act  = (size_t)RM * D;        // 4,194,304
    const size_t wsz  = (size_t)D * D;         // 1,048,576
    ushort* qa   = (ushort*)d_ws;              // bf16 activations
    ushort* ka   = qa + act;
    ushort* va   = ka + act;
    ushort* wqb  = va + act;                   // bf16 weights
    ushort* wkb  = wqb + wsz;
    ushort* wvb  = wkb + wsz;
    ushort* wob  = wvb + wsz;
    ushort* q_ws = wob + wsz;                  // projected head layouts
    ushort* k_ws = q_ws + act;
    ushort* vt_ws= k_ws + act;
    ushort* a_ws = vt_ws + act;                // attn output bf16 [RM, D]

    cvt3_kernel<<<dim3(act / 8 / 256, 3), 256, 0, stream>>>(query, key, value, qa, ka, va);
    cvt4_kernel<<<dim3(wsz / 8 / 256, 4), 256, 0, stream>>>(Wq, Wk, Wv, Wo, wqb, wkb, wvb, wob);

    proj_gemm<<<dim3(RM / 128, D / 64, 3), 256, 0, stream>>>(
        qa, ka, va, wqb, wkb, wvb, bq, bk, bv, q_ws, k_ws, vt_ws);

    attn_mfma<<<dim3(S / QBLK, B, H), 256, 0, stream>>>(q_ws, k_ws, vt_ws, kmask, a_ws);

    out_gemm<<<dim3(RM / 128, D / 64), 256, 0, stream>>>(a_ws, wob, bo, out);
}

// Round 4
// 183.854 us; speedup vs baseline: 8.8676x; 1.0885x over previous
//
#include <hip/hip_runtime.h>
#include <cmath>

namespace {

constexpr int S = 2048, B = 2, D = 1024, H = 16, E = 64;
constexpr int RM = S * B;
constexpr int K = D;
constexpr float MASKV = 1e18f;
constexpr int KVB = 64;
constexpr int SEGS_PER_HM = 48;   // t=0:2 segs, t=1..16:1, t=17..31:2

using s16x8 = __attribute__((ext_vector_type(8))) short;
using u16x8 = __attribute__((ext_vector_type(8))) unsigned short;
using f32x4 = __attribute__((ext_vector_type(4))) float;
typedef unsigned short ushort;
typedef unsigned int u32;

__device__ inline f32x4 mfma16(s16x8 a, s16x8 b, f32x4 c) {
    return __builtin_amdgcn_mfma_f32_16x16x32_bf16(a, b, c, 0, 0, 0);
}

__device__ inline ushort f2bf(float f) {
    unsigned u = __builtin_bit_cast(unsigned, f);
    u += 0x7fffu + ((u >> 16) & 1u);          // RNE
    return (ushort)(u >> 16);
}

__device__ inline void gload_lds16(const void* g, void* l) {
    __builtin_amdgcn_global_load_lds(
        (const __attribute__((address_space(1))) u32*)g,
        (__attribute__((address_space(3))) u32*)l,
        16, 0, 0);
}

// ---------------------------------------------------------------------------
// fp32 -> bf16 converters
// ---------------------------------------------------------------------------
__global__ __launch_bounds__(256)
void cvt3_kernel(const float* __restrict__ a, const float* __restrict__ b,
                 const float* __restrict__ c,
                 ushort* __restrict__ ao, ushort* __restrict__ bo2, ushort* __restrict__ co)
{
    const float* src = (blockIdx.y == 0) ? a : (blockIdx.y == 1) ? b : c;
    ushort* dst      = (blockIdx.y == 0) ? ao : (blockIdx.y == 1) ? bo2 : co;
    const size_t i = ((size_t)blockIdx.x * 256 + threadIdx.x) * 8;
    float4 x = *reinterpret_cast<const float4*>(&src[i]);
    float4 y = *reinterpret_cast<const float4*>(&src[i + 4]);
    u16x8 o;
    o[0]=f2bf(x.x); o[1]=f2bf(x.y); o[2]=f2bf(x.z); o[3]=f2bf(x.w);
    o[4]=f2bf(y.x); o[5]=f2bf(y.y); o[6]=f2bf(y.z); o[7]=f2bf(y.w);
    *reinterpret_cast<u16x8*>(&dst[i]) = o;
}

__global__ __launch_bounds__(256)
void cvt4_kernel(const float* __restrict__ a, const float* __restrict__ b,
                 const float* __restrict__ c, const float* __restrict__ d,
                 ushort* __restrict__ ao, ushort* __restrict__ bo2,
                 ushort* __restrict__ co, ushort* __restrict__ dd)
{
    const float* src = (blockIdx.y == 0) ? a : (blockIdx.y == 1) ? b : (blockIdx.y == 2) ? c : d;
    ushort* dst      = (blockIdx.y == 0) ? ao : (blockIdx.y == 1) ? bo2 : (blockIdx.y == 2) ? co : dd;
    const size_t i = ((size_t)blockIdx.x * 256 + threadIdx.x) * 8;
    float4 x = *reinterpret_cast<const float4*>(&src[i]);
    float4 y = *reinterpret_cast<const float4*>(&src[i + 4]);
    u16x8 o;
    o[0]=f2bf(x.x); o[1]=f2bf(x.y); o[2]=f2bf(x.z); o[3]=f2bf(x.w);
    o[4]=f2bf(y.x); o[5]=f2bf(y.y); o[6]=f2bf(y.z); o[7]=f2bf(y.w);
    *reinterpret_cast<u16x8*>(&dst[i]) = o;
}

// ---------------------------------------------------------------------------
// MFMA GEMM core (unchanged from R3)
// ---------------------------------------------------------------------------
__device__ inline void mm_core(const ushort* __restrict__ A, const ushort* __restrict__ W,
                               ushort* Albuf, ushort* Blbuf, int r0, int n0,
                               f32x4 (&acc)[4][2])
{
    const int t  = threadIdx.x;
    const int w  = t >> 6, l = t & 63;
    const int lr = l & 15, lg = l >> 4;
    const int wr = w >> 1, wc = w & 1;
    const int srow = t >> 3;
    const int gch  = (t & 7) ^ (srow & 7);

    for (int kt = 0; kt < K; kt += 64) {
        __syncthreads();
        #pragma unroll
        for (int c = 0; c < 4; ++c) {
            const int row = c * 32 + srow;
            gload_lds16(&A[(size_t)(r0 + row) * K + kt + gch * 8],
                        (char*)Albuf + c * 4096 + t * 16);
        }
        #pragma unroll
        for (int c = 0; c < 2; ++c) {
            const int row = c * 32 + srow;
            gload_lds16(&W[(size_t)(n0 + row) * K + kt + gch * 8],
                        (char*)Blbuf + c * 4096 + t * 16);
        }
        __syncthreads();

        #pragma unroll
        for (int ks = 0; ks < 2; ++ks) {
            s16x8 af[4], bf[2];
            #pragma unroll
            for (int mf = 0; mf < 4; ++mf) {
                const int row = wr * 64 + mf * 16 + lr;
                const int ch  = (ks * 4 + lg) ^ (row & 7);
                af[mf] = *reinterpret_cast<const s16x8*>((const char*)Albuf + row * 128 + ch * 16);
            }
            #pragma unroll
            for (int nf = 0; nf < 2; ++nf) {
                const int row = wc * 32 + nf * 16 + lr;
                const int ch  = (ks * 4 + lg) ^ (row & 7);
                bf[nf] = *reinterpret_cast<const s16x8*>((const char*)Blbuf + row * 128 + ch * 16);
            }
            #pragma unroll
            for (int mf = 0; mf < 4; ++mf)
                #pragma unroll
                for (int nf = 0; nf < 2; ++nf)
                    acc[mf][nf] = mfma16(af[mf], bf[nf], acc[mf][nf]);
        }
    }
}

__global__ __launch_bounds__(256)
void proj_gemm(const ushort* __restrict__ qa, const ushort* __restrict__ ka,
               const ushort* __restrict__ va,
               const ushort* __restrict__ wq, const ushort* __restrict__ wk,
               const ushort* __restrict__ wv,
               const float* __restrict__ bq, const float* __restrict__ bk,
               const float* __restrict__ bv,
               ushort* __restrict__ qd, ushort* __restrict__ kd, ushort* __restrict__ vtd)
{
    __shared__ ushort Albuf[128 * 64];
    __shared__ ushort Blbuf[64 * 64];
    const int z = blockIdx.z;
    const ushort* A    = (z == 0) ? qa : (z == 1) ? ka : va;
    const ushort* W    = (z == 0) ? wq : (z == 1) ? wk : wv;
    const float*  bias = (z == 0) ? bq : (z == 1) ? bk : bv;
    const int r0 = blockIdx.x * 128, n0 = blockIdx.y * 64;

    f32x4 acc[4][2] = {};
    mm_core(A, W, Albuf, Blbuf, r0, n0, acc);

    const int t = threadIdx.x, w = t >> 6, l = t & 63, lr = l & 15, lg = l >> 4;
    const int wr = w >> 1, wc = w & 1;
    #pragma unroll
    for (int mf = 0; mf < 4; ++mf) {
        #pragma unroll
        for (int nf = 0; nf < 2; ++nf) {
            const int n = n0 + wc * 32 + nf * 16 + lr;
            const int h = n >> 6, e = n & 63;
            const float bb = bias[n];
            #pragma unroll
            for (int rg = 0; rg < 4; ++rg) {
                const int r = r0 + wr * 64 + mf * 16 + lg * 4 + rg;
                const int i = r >> 1, m = r & 1;
                const ushort val = f2bf(acc[mf][nf][rg] + bb);
                if (z < 2) {
                    ushort* dst = (z == 0) ? qd : kd;
                    dst[(((size_t)(h * B + m)) * S + i) * E + e] = val;
                } else {
                    vtd[(((size_t)(h * B + m)) * E + e) * S + i] = val;
                }
            }
        }
    }
}

__global__ __launch_bounds__(256)
void out_gemm(const ushort* __restrict__ A, const ushort* __restrict__ W,
              const float* __restrict__ bias, float* __restrict__ Cout)
{
    __shared__ ushort Albuf[128 * 64];
    __shared__ ushort Blbuf[64 * 64];
    const int r0 = blockIdx.x * 128, n0 = blockIdx.y * 64;

    f32x4 acc[4][2] = {};
    mm_core(A, W, Albuf, Blbuf, r0, n0, acc);

    const int t = threadIdx.x, w = t >> 6, l = t & 63, lr = l & 15, lg = l >> 4;
    const int wr = w >> 1, wc = w & 1;
    #pragma unroll
    for (int mf = 0; mf < 4; ++mf) {
        #pragma unroll
        for (int nf = 0; nf < 2; ++nf) {
            const int n = n0 + wc * 32 + nf * 16 + lr;
            const float bb = bias[n];
            #pragma unroll
            for (int rg = 0; rg < 4; ++rg) {
                const int r = r0 + wr * 64 + mf * 16 + lg * 4 + rg;
                Cout[(size_t)r * D + n] = acc[mf][nf][rg] + bb;
            }
        }
    }
}

// ---------------------------------------------------------------------------
// first-unmasked-key prescan: fu[m] = min{j : key_mask[j,m]==0}, else S
// ---------------------------------------------------------------------------
__global__ __launch_bounds__(256)
void prescan_kernel(const int* __restrict__ km, int* __restrict__ fu)
{
    __shared__ int red[256];
    const int m = blockIdx.x, t = threadIdx.x;
    int best = S;
    for (int j = t; j < S; j += 256)
        if (km[(size_t)j * B + m] == 0) best = min(best, j);
    red[t] = best;
    __syncthreads();
    for (int s = 128; s > 0; s >>= 1) {
        if (t < s) red[t] = min(red[t], red[t + s]);
        __syncthreads();
    }
    if (t == 0) fu[m] = red[0];
}

// seg schedule helpers (static, data-independent)
__device__ inline int nseg_of(int t)  { return (t == 0 || t >= 17) ? 2 : 1; }
__device__ inline int segoff_of(int t){ return (t == 0) ? 0 : (t <= 16 ? t + 1 : 2 * t - 16); }

// ---------------------------------------------------------------------------
// Balanced MFMA flash attention, swapped QK^T, segment partials.
// Grid (48, B, H); 4 waves, wave wv owns q-rows [i0+wv*16, +16).
// Lane (lg, lcc): S^T regs hold (q = i0+wv*16+lcc, k = j0+jt*16+lg*4+r).
// LDS: linear 128B rows + XOR chunk swizzle (source pre-swizzled, rule #21).
// Writes unnormalized partial O (fp32) + (m,l) per row; combine pass merges.
// ---------------------------------------------------------------------------
__global__ __launch_bounds__(256)
void attn_seg(const ushort* __restrict__ q, const ushort* __restrict__ k,
              const ushort* __restrict__ vt, const int* __restrict__ key_mask,
              const int* __restrict__ fu,
              float* __restrict__ part_O, float* __restrict__ part_ml)
{
    const int s = blockIdx.x, m = blockIdx.y, h = blockIdx.z;
    int t, kk;
    if (s < 2)       { t = 0;               kk = s; }
    else if (s < 18) { t = s - 1;           kk = 0; }
    else             { t = 17 + ((s - 18) >> 1); kk = (s - 18) & 1; }
    const int i0 = t * 64;
    const int hm = h * B + m;
    const int seg = hm * SEGS_PER_HM + s;

    const int ns = nseg_of(t);
    const int h1 = (t == 0) ? 16 : ((t + 2) >> 1);
    const int jendT = (fu[m] < i0) ? (t + 1) : 32;      // in tiles (dynamic, correctness)
    const int lo = (ns == 2 && kk == 1) ? h1 : 0;
    const int hi = (ns == 2 && kk == 0) ? h1 : jendT;

    const ushort* Qb  = q  + (size_t)hm * S * E;
    const ushort* Kb  = k  + (size_t)hm * S * E;
    const ushort* Vtb = vt + (size_t)hm * E * S;

    __shared__ ushort Ks[KVB * 64];      // [key][e], linear 128B rows, XOR-chunk swizzled
    __shared__ ushort Vts[E * 64];       // [e][key], same
    __shared__ ushort Pw[4][16 * 72];    // per-wave P[q][k], 144B rows, XOR-chunk swizzled
    __shared__ float kms[KVB];

    const int tid = threadIdx.x;
    const int wv  = tid >> 6;
    const int l   = tid & 63;
    const int lg  = l >> 4;      // 0..3
    const int lcc = l & 15;      // 0..15
    const int a7  = lcc & 7;
    const int gi  = i0 + wv * 16 + lcc;   // this lane's q-row

    // staging map
    const int srow = tid >> 3;                 // 0..31
    const int sch  = (tid & 7) ^ (srow & 7);   // pre-swizzled source chunk

    // Q fragments (B operand): col = q-row (lcc), k-dim = e
    s16x8 qf0, qf1;
    {
        const ushort* qp = &Qb[(size_t)gi * E + lg * 8];
        qf0 = *reinterpret_cast<const s16x8*>(qp);
        qf1 = *reinterpret_cast<const s16x8*>(qp + 32);
    }

    float m_run = -INFINITY, l_run = 0.0f;
    f32x4 oacc[4] = {};

    for (int tj = lo; tj < hi; ++tj) {
        const int j0 = tj * 64;
        __syncthreads();
        #pragma unroll
        for (int c = 0; c < 2; ++c) {
            gload_lds16(&Kb[(size_t)(j0 + c * 32 + srow) * E + sch * 8],
                        (char*)Ks + c * 4096 + tid * 16);
            gload_lds16(&Vtb[(size_t)(c * 32 + srow) * S + j0 + sch * 8],
                        (char*)Vts + c * 4096 + tid * 16);
        }
        if (tid < KVB) kms[tid] = key_mask[(size_t)(j0 + tid) * B + m] ? MASKV : 0.0f;
        __syncthreads();

        // ---- S^T = K . Q^T : 4 key-groups of 16
        f32x4 sacc[4];
        #pragma unroll
        for (int jt = 0; jt < 4; ++jt) {
            const char* kb = (const char*)Ks + (jt * 16 + lcc) * 128;
            s16x8 kf0 = *reinterpret_cast<const s16x8*>(kb + (lg ^ a7) * 16);
            s16x8 kf1 = *reinterpret_cast<const s16x8*>(kb + ((lg ^ a7) ^ 4) * 16);
            f32x4 a = {};
            a = mfma16(kf0, qf0, a);
            a = mfma16(kf1, qf1, a);
            sacc[jt] = a;
        }

        // ---- scale + masks (exact fp32 reference semantics)
        if (j0 >= i0) {   // tile touches/passes the diagonal: causal term needed
            #pragma unroll
            for (int jt = 0; jt < 4; ++jt) {
                const float4 km4 = *reinterpret_cast<const float4*>(&kms[jt * 16 + lg * 4]);
                const int jmi = j0 + jt * 16 + lg * 4 - gi;
                #pragma unroll
                for (int r = 0; r < 4; ++r) {
                    float sc = sacc[jt][r] * 0.125f;
                    sc -= ((const float*)&km4)[r];
                    sc -= (jmi + r > 0) ? MASKV : 0.0f;
                    sacc[jt][r] = sc;
                }
            }
        } else {
            #pragma unroll
            for (int jt = 0; jt < 4; ++jt) {
                const float4 km4 = *reinterpret_cast<const float4*>(&kms[jt * 16 + lg * 4]);
                #pragma unroll
                for (int r = 0; r < 4; ++r)
                    sacc[jt][r] = sacc[jt][r] * 0.125f - ((const float*)&km4)[r];
            }
        }

        // ---- online softmax: all 16 values belong to q-row `gi`
        float mm = -INFINITY;
        #pragma unroll
        for (int jt = 0; jt < 4; ++jt)
            #pragma unroll
            for (int r = 0; r < 4; ++r) mm = fmaxf(mm, sacc[jt][r]);
        mm = fmaxf(mm, __shfl_xor(mm, 16));
        mm = fmaxf(mm, __shfl_xor(mm, 32));
        const float m_new = fmaxf(m_run, mm);
        const float scale = __expf(m_run - m_new);
        m_run = m_new;

        float psum = 0.0f;
        #pragma unroll
        for (int jt = 0; jt < 4; ++jt) {
            const int pch = ((jt * 2 + (lg >> 1)) ^ a7) * 8 + (lg & 1) * 4;
            ushort* pw = &Pw[wv][lcc * 72 + pch];
            #pragma unroll
            for (int r = 0; r < 4; ++r) {
                const float p = __expf(sacc[jt][r] - m_new);
                psum += p;
                pw[r] = f2bf(p);
            }
        }
        psum += __shfl_xor(psum, 16);
        psum += __shfl_xor(psum, 32);
        l_run = l_run * scale + psum;

        // ---- rescale O: scale for accumulator row (lg*4+r) lives at lane lcc==lg*4+r
        float scr[4];
        #pragma unroll
        for (int r = 0; r < 4; ++r)
            scr[r] = __shfl(scale, (l & 48) | (lg * 4 + r));
        #pragma unroll
        for (int et = 0; et < 4; ++et)
            #pragma unroll
            for (int r = 0; r < 4; ++r) oacc[et][r] *= scr[r];

        // ---- PV: A = P[q][k] (per-wave LDS), B = V^T[e][k]
        {
            const char* pb = (const char*)&Pw[wv][lcc * 72];
            s16x8 pf0 = *reinterpret_cast<const s16x8*>(pb + (lg ^ a7) * 16);
            s16x8 pf1 = *reinterpret_cast<const s16x8*>(pb + ((lg ^ a7) ^ 4) * 16);
            #pragma unroll
            for (int et = 0; et < 4; ++et) {
                const char* vb = (const char*)Vts + (et * 16 + lcc) * 128;
                s16x8 vf0 = *reinterpret_cast<const s16x8*>(vb + (lg ^ a7) * 16);
                s16x8 vf1 = *reinterpret_cast<const s16x8*>(vb + ((lg ^ a7) ^ 4) * 16);
                oacc[et] = mfma16(pf0, vf0, oacc[et]);
                oacc[et] = mfma16(pf1, vf1, oacc[et]);
            }
        }
    }

    // ---- write unnormalized partials
    #pragma unroll
    for (int et = 0; et < 4; ++et)
        #pragma unroll
        for (int r = 0; r < 4; ++r)
            part_O[((size_t)seg * 64 + wv * 16 + lg * 4 + r) * 64 + et * 16 + lcc] = oacc[et][r];
    if (lg == 0) {
        part_ml[((size_t)seg * 64 + wv * 16 + lcc) * 2]     = m_run;
        part_ml[((size_t)seg * 64 + wv * 16 + lcc) * 2 + 1] = l_run;
    }
}

// ---------------------------------------------------------------------------
// combine: merge 1-2 segments per q-tile, normalize, emit bf16 [r][n] layout
// ---------------------------------------------------------------------------
__global__ __launch_bounds__(256)
void attn_combine(const float* __restrict__ part_O, const float* __restrict__ part_ml,
                  ushort* __restrict__ a_ws)
{
    const int t = blockIdx.x, m = blockIdx.y, h = blockIdx.z;
    const int hm = h * B + m;
    const int ns = nseg_of(t);
    const int seg0 = hm * SEGS_PER_HM + segoff_of(t);

    const int tid = threadIdx.x;
    const int row = tid >> 2;            // 0..63
    const int e0  = (tid & 3) * 16;
    const int gi  = t * 64 + row;

    const size_t r0 = (size_t)seg0 * 64 + row;
    const float m0 = part_ml[r0 * 2], l0 = part_ml[r0 * 2 + 1];
    float w0, w1 = 0.0f, linv;
    size_t r1 = 0;
    if (ns == 2) {
        r1 = ((size_t)(seg0 + 1)) * 64 + row;
        const float m1 = part_ml[r1 * 2], l1 = part_ml[r1 * 2 + 1];
        const float ms = fmaxf(m0, m1);
        w0 = __expf(m0 - ms);
        w1 = __expf(m1 - ms);
        linv = 1.0f / (l0 * w0 + l1 * w1);
    } else {
        w0 = 1.0f;
        linv = 1.0f / l0;
    }

    ushort* dst = a_ws + ((size_t)gi * B + m) * D + h * E + e0;
    #pragma unroll
    for (int c = 0; c < 4; ++c) {
        float4 o0 = *reinterpret_cast<const float4*>(&part_O[r0 * 64 + e0 + c * 4]);
        float ov[4] = {o0.x, o0.y, o0.z, o0.w};
        if (ns == 2) {
            float4 o1 = *reinterpret_cast<const float4*>(&part_O[r1 * 64 + e0 + c * 4]);
            ov[0] = ov[0] * w0 + o1.x * w1;
            ov[1] = ov[1] * w0 + o1.y * w1;
            ov[2] = ov[2] * w0 + o1.z * w1;
            ov[3] = ov[3] * w0 + o1.w * w1;
        } else {
            ov[0] *= w0; ov[1] *= w0; ov[2] *= w0; ov[3] *= w0;
        }
        dst[c * 4 + 0] = f2bf(ov[0] * linv);
        dst[c * 4 + 1] = f2bf(ov[1] * linv);
        dst[c * 4 + 2] = f2bf(ov[2] * linv);
        dst[c * 4 + 3] = f2bf(ov[3] * linv);
    }
}

} // anonymous namespace

extern "C" void kernel_launch(void* const* d_in, const int* in_sizes, int n_in,
                              void* d_out, int out_size, void* d_ws, size_t ws_size,
                              hipStream_t stream)
{
    const float* query = (const float*)d_in[0];
    const float* key   = (const float*)d_in[1];
    const float* value = (const float*)d_in[2];
    const int*   kmask = (const int*)  d_in[3];
    const float* Wq    = (const float*)d_in[4];
    const float* bq    = (const float*)d_in[5];
    const float* Wk    = (const float*)d_in[6];
    const float* bk    = (const float*)d_in[7];
    const float* Wv    = (const float*)d_in[8];
    const float* bv    = (const float*)d_in[9];
    const float* Wo    = (const float*)d_in[10];
    const float* bo    = (const float*)d_in[11];
    float* out = (float*)d_out;

    const size_t act = (size_t)RM * D;     // 4,194,304 elems
    const size_t wsz = (size_t)D * D;      // 1,048,576 elems
    ushort* wob  = (ushort*)d_ws;          // output weight FIRST (alive till end)
    ushort* wqb  = wob + wsz;              // \  dead after proj_gemm:
    ushort* wkb  = wqb + wsz;              //  | part_ml aliases wqb
    ushort* wvb  = wkb + wsz;              // /
    ushort* qa   = wvb + wsz;              // \  dead after proj_gemm:
    ushort* ka   = qa + act;               //  | part_O aliases qa..va (exact fit)
    ushort* va   = ka + act;               // /
    ushort* q_ws = va + act;
    ushort* k_ws = q_ws + act;
    ushort* vt_ws= k_ws + act;
    ushort* a_ws = vt_ws + act;
    int*    fu   = (int*)(a_ws + act);
    float* part_O  = (float*)qa;           // 1536*64*64 f32 == 3*act ushorts
    float* part_ml = (float*)wqb;          // 1536*64*2 f32 (<2MB, fits wqb)

    cvt3_kernel<<<dim3(act / 8 / 256, 3), 256, 0, stream>>>(query, key, value, qa, ka, va);
    cvt4_kernel<<<dim3(wsz / 8 / 256, 4), 256, 0, stream>>>(Wq, Wk, Wv, Wo, wqb, wkb, wvb, wob);
    prescan_kernel<<<dim3(B), 256, 0, stream>>>(kmask, fu);

    proj_gemm<<<dim3(RM / 128, D / 64, 3), 256, 0, stream>>>(
        qa, ka, va, wqb, wkb, wvb, bq, bk, bv, q_ws, k_ws, vt_ws);

    attn_seg<<<dim3(SEGS_PER_HM, B, H), 256, 0, stream>>>(
        q_ws, k_ws, vt_ws, kmask, fu, part_O, part_ml);

    attn_combine<<<dim3(S / 64, B, H), 256, 0, stream>>>(part_O, part_ml, a_ws);

    out_gemm<<<dim3(RM / 128, D / 64), 256, 0, stream>>>(a_ws, wob, bo, out);
}

// Round 5
// 174.093 us; speedup vs baseline: 9.3648x; 1.0561x over previous
//
#include <hip/hip_runtime.h>
#include <cmath>

namespace {

constexpr int S = 2048, B = 2, D = 1024, H = 16, E = 64;
constexpr int RM = S * B;
constexpr int K = D;
constexpr float MASKV = 1e18f;
constexpr int KVB = 64;
constexpr int SEGS_PER_HM = 48;   // t=0:2 segs, t=1..16:1, t=17..31:2

using s16x8 = __attribute__((ext_vector_type(8))) short;
using u16x8 = __attribute__((ext_vector_type(8))) unsigned short;
using f32x4 = __attribute__((ext_vector_type(4))) float;
typedef unsigned short ushort;
typedef unsigned int u32;

__device__ inline f32x4 mfma16(s16x8 a, s16x8 b, f32x4 c) {
    return __builtin_amdgcn_mfma_f32_16x16x32_bf16(a, b, c, 0, 0, 0);
}

__device__ inline ushort f2bf(float f) {
    unsigned u = __builtin_bit_cast(unsigned, f);
    u += 0x7fffu + ((u >> 16) & 1u);          // RNE
    return (ushort)(u >> 16);
}

__device__ inline void gload_lds16(const void* g, void* l) {
    __builtin_amdgcn_global_load_lds(
        (const __attribute__((address_space(1))) u32*)g,
        (__attribute__((address_space(3))) u32*)l,
        16, 0, 0);
}

// ---------------------------------------------------------------------------
// fp32 -> bf16 converters
// ---------------------------------------------------------------------------
__global__ __launch_bounds__(256)
void cvt3_kernel(const float* __restrict__ a, const float* __restrict__ b,
                 const float* __restrict__ c,
                 ushort* __restrict__ ao, ushort* __restrict__ bo2, ushort* __restrict__ co)
{
    const float* src = (blockIdx.y == 0) ? a : (blockIdx.y == 1) ? b : c;
    ushort* dst      = (blockIdx.y == 0) ? ao : (blockIdx.y == 1) ? bo2 : co;
    const size_t i = ((size_t)blockIdx.x * 256 + threadIdx.x) * 8;
    float4 x = *reinterpret_cast<const float4*>(&src[i]);
    float4 y = *reinterpret_cast<const float4*>(&src[i + 4]);
    u16x8 o;
    o[0]=f2bf(x.x); o[1]=f2bf(x.y); o[2]=f2bf(x.z); o[3]=f2bf(x.w);
    o[4]=f2bf(y.x); o[5]=f2bf(y.y); o[6]=f2bf(y.z); o[7]=f2bf(y.w);
    *reinterpret_cast<u16x8*>(&dst[i]) = o;
}

__global__ __launch_bounds__(256)
void cvt4_kernel(const float* __restrict__ a, const float* __restrict__ b,
                 const float* __restrict__ c, const float* __restrict__ d,
                 ushort* __restrict__ ao, ushort* __restrict__ bo2,
                 ushort* __restrict__ co, ushort* __restrict__ dd)
{
    const float* src = (blockIdx.y == 0) ? a : (blockIdx.y == 1) ? b : (blockIdx.y == 2) ? c : d;
    ushort* dst      = (blockIdx.y == 0) ? ao : (blockIdx.y == 1) ? bo2 : (blockIdx.y == 2) ? co : dd;
    const size_t i = ((size_t)blockIdx.x * 256 + threadIdx.x) * 8;
    float4 x = *reinterpret_cast<const float4*>(&src[i]);
    float4 y = *reinterpret_cast<const float4*>(&src[i + 4]);
    u16x8 o;
    o[0]=f2bf(x.x); o[1]=f2bf(x.y); o[2]=f2bf(x.z); o[3]=f2bf(x.w);
    o[4]=f2bf(y.x); o[5]=f2bf(y.y); o[6]=f2bf(y.z); o[7]=f2bf(y.w);
    *reinterpret_cast<u16x8*>(&dst[i]) = o;
}

// ---------------------------------------------------------------------------
// MFMA GEMM core, 128x128 tile (m97 shape): 4 waves, each a 64x64 quadrant
// (4x4 fragments of 16x16x32). global_load_lds staging, linear LDS +
// XOR-chunk swizzle with pre-swizzled global source (rule #21).
// ---------------------------------------------------------------------------
__device__ inline void mm_core2(const ushort* __restrict__ A, const ushort* __restrict__ W,
                                ushort* Albuf, ushort* Blbuf, int r0, int n0,
                                f32x4 (&acc)[4][4])
{
    const int t  = threadIdx.x;
    const int w  = t >> 6, l = t & 63;
    const int lr = l & 15, lg = l >> 4;
    const int wr = w >> 1, wc = w & 1;
    const int srow = t >> 3;
    const int gch  = (t & 7) ^ (srow & 7);

    for (int kt = 0; kt < K; kt += 64) {
        __syncthreads();
        #pragma unroll
        for (int c = 0; c < 4; ++c) {
            gload_lds16(&A[(size_t)(r0 + c * 32 + srow) * K + kt + gch * 8],
                        (char*)Albuf + c * 4096 + t * 16);
            gload_lds16(&W[(size_t)(n0 + c * 32 + srow) * K + kt + gch * 8],
                        (char*)Blbuf + c * 4096 + t * 16);
        }
        __syncthreads();

        #pragma unroll
        for (int ks = 0; ks < 2; ++ks) {
            s16x8 af[4], bf[4];
            #pragma unroll
            for (int mf = 0; mf < 4; ++mf) {
                const int row = wr * 64 + mf * 16 + lr;
                const int ch  = (ks * 4 + lg) ^ (row & 7);
                af[mf] = *reinterpret_cast<const s16x8*>((const char*)Albuf + row * 128 + ch * 16);
            }
            #pragma unroll
            for (int nf = 0; nf < 4; ++nf) {
                const int row = wc * 64 + nf * 16 + lr;
                const int ch  = (ks * 4 + lg) ^ (row & 7);
                bf[nf] = *reinterpret_cast<const s16x8*>((const char*)Blbuf + row * 128 + ch * 16);
            }
            #pragma unroll
            for (int mf = 0; mf < 4; ++mf)
                #pragma unroll
                for (int nf = 0; nf < 4; ++nf)
                    acc[mf][nf] = mfma16(af[mf], bf[nf], acc[mf][nf]);
        }
    }
}

__global__ __launch_bounds__(256)
void proj_gemm(const ushort* __restrict__ qa, const ushort* __restrict__ ka,
               const ushort* __restrict__ va,
               const ushort* __restrict__ wq, const ushort* __restrict__ wk,
               const ushort* __restrict__ wv,
               const float* __restrict__ bq, const float* __restrict__ bk,
               const float* __restrict__ bv,
               ushort* __restrict__ qd, ushort* __restrict__ kd, ushort* __restrict__ vtd)
{
    __shared__ ushort Albuf[128 * 64];
    __shared__ ushort Blbuf[128 * 64];
    const int z = blockIdx.z;
    const ushort* A    = (z == 0) ? qa : (z == 1) ? ka : va;
    const ushort* W    = (z == 0) ? wq : (z == 1) ? wk : wv;
    const float*  bias = (z == 0) ? bq : (z == 1) ? bk : bv;
    const int r0 = blockIdx.x * 128, n0 = blockIdx.y * 128;

    f32x4 acc[4][4] = {};
    mm_core2(A, W, Albuf, Blbuf, r0, n0, acc);

    const int t = threadIdx.x, w = t >> 6, l = t & 63, lr = l & 15, lg = l >> 4;
    const int wr = w >> 1, wc = w & 1;
    #pragma unroll
    for (int mf = 0; mf < 4; ++mf) {
        #pragma unroll
        for (int nf = 0; nf < 4; ++nf) {
            const int n = n0 + wc * 64 + nf * 16 + lr;
            const int h = n >> 6, e = n & 63;
            const float bb = bias[n];
            #pragma unroll
            for (int rg = 0; rg < 4; ++rg) {
                const int r = r0 + wr * 64 + mf * 16 + lg * 4 + rg;
                const int i = r >> 1, m = r & 1;
                const ushort val = f2bf(acc[mf][nf][rg] + bb);
                if (z < 2) {
                    ushort* dst = (z == 0) ? qd : kd;
                    dst[(((size_t)(h * B + m)) * S + i) * E + e] = val;
                } else {
                    vtd[(((size_t)(h * B + m)) * E + e) * S + i] = val;
                }
            }
        }
    }
}

__global__ __launch_bounds__(256)
void out_gemm(const ushort* __restrict__ A, const ushort* __restrict__ W,
              const float* __restrict__ bias, float* __restrict__ Cout)
{
    __shared__ ushort Albuf[128 * 64];
    __shared__ ushort Blbuf[128 * 64];
    const int r0 = blockIdx.x * 128, n0 = blockIdx.y * 128;

    f32x4 acc[4][4] = {};
    mm_core2(A, W, Albuf, Blbuf, r0, n0, acc);

    const int t = threadIdx.x, w = t >> 6, l = t & 63, lr = l & 15, lg = l >> 4;
    const int wr = w >> 1, wc = w & 1;
    #pragma unroll
    for (int mf = 0; mf < 4; ++mf) {
        #pragma unroll
        for (int nf = 0; nf < 4; ++nf) {
            const int n = n0 + wc * 64 + nf * 16 + lr;
            const float bb = bias[n];
            #pragma unroll
            for (int rg = 0; rg < 4; ++rg) {
                const int r = r0 + wr * 64 + mf * 16 + lg * 4 + rg;
                Cout[(size_t)r * D + n] = acc[mf][nf][rg] + bb;
            }
        }
    }
}

// ---------------------------------------------------------------------------
// prescan: fu[m] = min{j : key_mask[j,m]==0} (else S); kmf[m][j] = mask * 1e18
// ---------------------------------------------------------------------------
__global__ __launch_bounds__(256)
void prescan_kernel(const int* __restrict__ km, int* __restrict__ fu,
                    float* __restrict__ kmf)
{
    __shared__ int red[256];
    const int m = blockIdx.x, t = threadIdx.x;
    int best = S;
    for (int j = t; j < S; j += 256) {
        const int v = km[(size_t)j * B + m];
        kmf[(size_t)m * S + j] = v ? MASKV : 0.0f;
        if (v == 0) best = min(best, j);
    }
    red[t] = best;
    __syncthreads();
    for (int s = 128; s > 0; s >>= 1) {
        if (t < s) red[t] = min(red[t], red[t + s]);
        __syncthreads();
    }
    if (t == 0) fu[m] = red[0];
}

// seg schedule helpers (static, data-independent)
__device__ inline int nseg_of(int t)  { return (t == 0 || t >= 17) ? 2 : 1; }
__device__ inline int segoff_of(int t){ return (t == 0) ? 0 : (t <= 16 ? t + 1 : 2 * t - 16); }

// ---------------------------------------------------------------------------
// Balanced MFMA flash attention, swapped QK^T, 2-phase prefetch double-buffer:
// issue global_load_lds for tile tj+1, compute tile tj, ONE barrier per tile
// (vmcnt drain lands after ~1000cy of compute -> load latency hidden).
// ---------------------------------------------------------------------------
__global__ __launch_bounds__(256)
void attn_seg(const ushort* __restrict__ q, const ushort* __restrict__ k,
              const ushort* __restrict__ vt, const int* __restrict__ fu,
              const float* __restrict__ kmf,
              float* __restrict__ part_O, float* __restrict__ part_ml)
{
    const int s = blockIdx.x, m = blockIdx.y, h = blockIdx.z;
    int t, kk;
    if (s < 2)       { t = 0;               kk = s; }
    else if (s < 18) { t = s - 1;           kk = 0; }
    else             { t = 17 + ((s - 18) >> 1); kk = (s - 18) & 1; }
    const int i0 = t * 64;
    const int hm = h * B + m;
    const int seg = hm * SEGS_PER_HM + s;

    const int ns = nseg_of(t);
    const int h1 = (t == 0) ? 16 : ((t + 2) >> 1);
    const int jendT = (fu[m] < i0) ? (t + 1) : 32;
    const int lo = (ns == 2 && kk == 1) ? h1 : 0;
    const int hi = (ns == 2 && kk == 0) ? h1 : jendT;

    const ushort* Qb  = q  + (size_t)hm * S * E;
    const ushort* Kb  = k  + (size_t)hm * S * E;
    const ushort* Vtb = vt + (size_t)hm * E * S;
    const float*  kmfm = kmf + (size_t)m * S;

    __shared__ ushort Ks[2][KVB * 64];   // [key][e], 128B rows, XOR-chunk swizzled
    __shared__ ushort Vts[2][E * 64];    // [e][key]
    __shared__ ushort Pw[4][16 * 64];    // per-wave P[q][k], 128B rows, swizzled

    const int tid = threadIdx.x;
    const int wv  = tid >> 6;
    const int l   = tid & 63;
    const int lg  = l >> 4;      // 0..3
    const int lcc = l & 15;      // 0..15
    const int a7  = lcc & 7;
    const int gi  = i0 + wv * 16 + lcc;

    const int srow = tid >> 3;                 // 0..31
    const int sch  = (tid & 7) ^ (srow & 7);   // pre-swizzled source chunk

    // Q fragments (B operand of swapped QK^T)
    s16x8 qf0, qf1;
    {
        const ushort* qp = &Qb[(size_t)gi * E + lg * 8];
        qf0 = *reinterpret_cast<const s16x8*>(qp);
        qf1 = *reinterpret_cast<const s16x8*>(qp + 32);
    }

    float m_run = -INFINITY, l_run = 0.0f;
    f32x4 oacc[4] = {};

    // stage tile `tj` into buffer `buf`
    auto STAGE = [&](int buf, int tj) {
        const int j0 = tj * 64;
        gload_lds16(&Kb[(size_t)(j0 + srow) * E + sch * 8],
                    (char*)&Ks[buf][0] + tid * 16);
        gload_lds16(&Kb[(size_t)(j0 + 32 + srow) * E + sch * 8],
                    (char*)&Ks[buf][0] + 4096 + tid * 16);
        gload_lds16(&Vtb[(size_t)srow * S + j0 + sch * 8],
                    (char*)&Vts[buf][0] + tid * 16);
        gload_lds16(&Vtb[(size_t)(32 + srow) * S + j0 + sch * 8],
                    (char*)&Vts[buf][0] + 4096 + tid * 16);
    };

    STAGE(0, lo);
    __syncthreads();
    int cur = 0;

    for (int tj = lo; tj < hi; ++tj) {
        const int j0 = tj * 64;
        if (tj + 1 < hi) STAGE(cur ^ 1, tj + 1);   // prefetch next tile

        // mask vector loads (L2-resident table), consumed after the MFMAs
        float4 km4[4];
        #pragma unroll
        for (int jt = 0; jt < 4; ++jt)
            km4[jt] = *reinterpret_cast<const float4*>(&kmfm[j0 + jt * 16 + lg * 4]);

        // ---- S^T = K . Q^T
        f32x4 sacc[4];
        #pragma unroll
        for (int jt = 0; jt < 4; ++jt) {
            const char* kb = (const char*)&Ks[cur][0] + (jt * 16 + lcc) * 128;
            s16x8 kf0 = *reinterpret_cast<const s16x8*>(kb + (lg ^ a7) * 16);
            s16x8 kf1 = *reinterpret_cast<const s16x8*>(kb + ((lg ^ a7) ^ 4) * 16);
            f32x4 a = {};
            a = mfma16(kf0, qf0, a);
            a = mfma16(kf1, qf1, a);
            sacc[jt] = a;
        }

        // ---- scale + masks (exact fp32 reference semantics)
        if (j0 >= i0) {
            #pragma unroll
            for (int jt = 0; jt < 4; ++jt) {
                const int jmi = j0 + jt * 16 + lg * 4 - gi;
                #pragma unroll
                for (int r = 0; r < 4; ++r) {
                    float sc = sacc[jt][r] * 0.125f;
                    sc -= ((const float*)&km4[jt])[r];
                    sc -= (jmi + r > 0) ? MASKV : 0.0f;
                    sacc[jt][r] = sc;
                }
            }
        } else {
            #pragma unroll
            for (int jt = 0; jt < 4; ++jt)
                #pragma unroll
                for (int r = 0; r < 4; ++r)
                    sacc[jt][r] = sacc[jt][r] * 0.125f - ((const float*)&km4[jt])[r];
        }

        // ---- online softmax (all 16 values belong to q-row gi)
        float mm = -INFINITY;
        #pragma unroll
        for (int jt = 0; jt < 4; ++jt)
            #pragma unroll
            for (int r = 0; r < 4; ++r) mm = fmaxf(mm, sacc[jt][r]);
        mm = fmaxf(mm, __shfl_xor(mm, 16));
        mm = fmaxf(mm, __shfl_xor(mm, 32));
        const float m_new = fmaxf(m_run, mm);
        const float scale = __expf(m_run - m_new);
        m_run = m_new;

        float psum = 0.0f;
        #pragma unroll
        for (int jt = 0; jt < 4; ++jt) {
            const int pch = ((jt * 2 + (lg >> 1)) ^ a7) * 8 + (lg & 1) * 4;
            ushort* pw = &Pw[wv][lcc * 64 + pch];
            #pragma unroll
            for (int r = 0; r < 4; ++r) {
                const float p = __expf(sacc[jt][r] - m_new);
                psum += p;
                pw[r] = f2bf(p);
            }
        }
        psum += __shfl_xor(psum, 16);
        psum += __shfl_xor(psum, 32);
        l_run = l_run * scale + psum;

        // ---- rescale O (scale for acc row lg*4+r lives at lane lcc==lg*4+r)
        float scr[4];
        #pragma unroll
        for (int r = 0; r < 4; ++r)
            scr[r] = __shfl(scale, (l & 48) | (lg * 4 + r));
        #pragma unroll
        for (int et = 0; et < 4; ++et)
            #pragma unroll
            for (int r = 0; r < 4; ++r) oacc[et][r] *= scr[r];

        // ---- PV: A = P (per-wave LDS), B = V^T
        {
            const char* pb = (const char*)&Pw[wv][lcc * 64];
            s16x8 pf0 = *reinterpret_cast<const s16x8*>(pb + (lg ^ a7) * 16);
            s16x8 pf1 = *reinterpret_cast<const s16x8*>(pb + ((lg ^ a7) ^ 4) * 16);
            #pragma unroll
            for (int et = 0; et < 4; ++et) {
                const char* vb = (const char*)&Vts[cur][0] + (et * 16 + lcc) * 128;
                s16x8 vf0 = *reinterpret_cast<const s16x8*>(vb + (lg ^ a7) * 16);
                s16x8 vf1 = *reinterpret_cast<const s16x8*>(vb + ((lg ^ a7) ^ 4) * 16);
                oacc[et] = mfma16(pf0, vf0, oacc[et]);
                oacc[et] = mfma16(pf1, vf1, oacc[et]);
            }
        }

        __syncthreads();   // next buffer staged + everyone done reading cur
        cur ^= 1;
    }

    // ---- write unnormalized partials
    #pragma unroll
    for (int et = 0; et < 4; ++et)
        #pragma unroll
        for (int r = 0; r < 4; ++r)
            part_O[((size_t)seg * 64 + wv * 16 + lg * 4 + r) * 64 + et * 16 + lcc] = oacc[et][r];
    if (lg == 0) {
        part_ml[((size_t)seg * 64 + wv * 16 + lcc) * 2]     = m_run;
        part_ml[((size_t)seg * 64 + wv * 16 + lcc) * 2 + 1] = l_run;
    }
}

// ---------------------------------------------------------------------------
// combine: merge 1-2 segments per q-tile, normalize, emit bf16 [r][n]
// ---------------------------------------------------------------------------
__global__ __launch_bounds__(256)
void attn_combine(const float* __restrict__ part_O, const float* __restrict__ part_ml,
                  ushort* __restrict__ a_ws)
{
    const int t = blockIdx.x, m = blockIdx.y, h = blockIdx.z;
    const int hm = h * B + m;
    const int ns = nseg_of(t);
    const int seg0 = hm * SEGS_PER_HM + segoff_of(t);

    const int tid = threadIdx.x;
    const int row = tid >> 2;
    const int e0  = (tid & 3) * 16;
    const int gi  = t * 64 + row;

    const size_t r0 = (size_t)seg0 * 64 + row;
    const float m0 = part_ml[r0 * 2], l0 = part_ml[r0 * 2 + 1];
    float w0, w1 = 0.0f, linv;
    size_t r1 = 0;
    if (ns == 2) {
        r1 = ((size_t)(seg0 + 1)) * 64 + row;
        const float m1 = part_ml[r1 * 2], l1 = part_ml[r1 * 2 + 1];
        const float ms = fmaxf(m0, m1);
        w0 = __expf(m0 - ms);
        w1 = __expf(m1 - ms);
        linv = 1.0f / (l0 * w0 + l1 * w1);
    } else {
        w0 = 1.0f;
        linv = 1.0f / l0;
    }

    ushort* dst = a_ws + ((size_t)gi * B + m) * D + h * E + e0;
    #pragma unroll
    for (int c = 0; c < 4; ++c) {
        float4 o0 = *reinterpret_cast<const float4*>(&part_O[r0 * 64 + e0 + c * 4]);
        float ov[4] = {o0.x, o0.y, o0.z, o0.w};
        if (ns == 2) {
            float4 o1 = *reinterpret_cast<const float4*>(&part_O[r1 * 64 + e0 + c * 4]);
            ov[0] = ov[0] * w0 + o1.x * w1;
            ov[1] = ov[1] * w0 + o1.y * w1;
            ov[2] = ov[2] * w0 + o1.z * w1;
            ov[3] = ov[3] * w0 + o1.w * w1;
        } else {
            ov[0] *= w0; ov[1] *= w0; ov[2] *= w0; ov[3] *= w0;
        }
        dst[c * 4 + 0] = f2bf(ov[0] * linv);
        dst[c * 4 + 1] = f2bf(ov[1] * linv);
        dst[c * 4 + 2] = f2bf(ov[2] * linv);
        dst[c * 4 + 3] = f2bf(ov[3] * linv);
    }
}

} // anonymous namespace

extern "C" void kernel_launch(void* const* d_in, const int* in_sizes, int n_in,
                              void* d_out, int out_size, void* d_ws, size_t ws_size,
                              hipStream_t stream)
{
    const float* query = (const float*)d_in[0];
    const float* key   = (const float*)d_in[1];
    const float* value = (const float*)d_in[2];
    const int*   kmask = (const int*)  d_in[3];
    const float* Wq    = (const float*)d_in[4];
    const float* bq    = (const float*)d_in[5];
    const float* Wk    = (const float*)d_in[6];
    const float* bk    = (const float*)d_in[7];
    const float* Wv    = (const float*)d_in[8];
    const float* bv    = (const float*)d_in[9];
    const float* Wo    = (const float*)d_in[10];
    const float* bo    = (const float*)d_in[11];
    float* out = (float*)d_out;

    const size_t act = (size_t)RM * D;     // 4,194,304 elems
    const size_t wsz = (size_t)D * D;      // 1,048,576 elems
    ushort* wob  = (ushort*)d_ws;          // output weight (alive till end)
    ushort* wqb  = wob + wsz;              // part_ml aliases wqb after proj
    ushort* wkb  = wqb + wsz;              // fu+kmf alias wkb after proj
    ushort* wvb  = wkb + wsz;
    ushort* qa   = wvb + wsz;              // part_O aliases qa..va after proj
    ushort* ka   = qa + act;
    ushort* va   = ka + act;
    ushort* q_ws = va + act;
    ushort* k_ws = q_ws + act;
    ushort* vt_ws= k_ws + act;
    ushort* a_ws = vt_ws + act;
    float* part_O  = (float*)qa;           // 1536*64*64 f32 == 3*act ushorts
    float* part_ml = (float*)wqb;          // 786 KB < 2 MB
    int*   fu      = (int*)wkb;            // 16 B
    float* kmf     = (float*)wkb + 8;      // S*B f32 = 16 KB < 2 MB

    cvt3_kernel<<<dim3(act / 8 / 256, 3), 256, 0, stream>>>(query, key, value, qa, ka, va);
    cvt4_kernel<<<dim3(wsz / 8 / 256, 4), 256, 0, stream>>>(Wq, Wk, Wv, Wo, wqb, wkb, wvb, wob);

    proj_gemm<<<dim3(RM / 128, D / 128, 3), 256, 0, stream>>>(
        qa, ka, va, wqb, wkb, wvb, bq, bk, bv, q_ws, k_ws, vt_ws);

    prescan_kernel<<<dim3(B), 256, 0, stream>>>(kmask, fu, kmf);   // after proj: wkb is dead

    attn_seg<<<dim3(SEGS_PER_HM, B, H), 256, 0, stream>>>(
        q_ws, k_ws, vt_ws, fu, kmf, part_O, part_ml);

    attn_combine<<<dim3(S / 64, B, H), 256, 0, stream>>>(part_O, part_ml, a_ws);

    out_gemm<<<dim3(RM / 128, D / 128), 256, 0, stream>>>(a_ws, wob, bo, out);
}

// Round 7
// 151.382 us; speedup vs baseline: 10.7697x; 1.1500x over previous
//
#include <hip/hip_runtime.h>
#include <cmath>

namespace {

constexpr int S = 2048, B = 2, D = 1024, H = 16, E = 64;
constexpr int RM = S * B;
constexpr int K = D;
constexpr int KVB = 64;
constexpr int SEGS_PER_HM = 48;   // t=0:2 segs, t=1..16:1, t=17..31:2

// exp2-domain constants: score2 = raw*(0.125*log2e) - km*KMB2 - causal*KMB2
constexpr float QSCL = 0.18033688011112043f;      // 0.125 * log2(e)
constexpr float KMB2 = 1.4426950408889634e18f;    // 1e18 * log2(e)

using s16x8 = __attribute__((ext_vector_type(8))) short;
using u16x8 = __attribute__((ext_vector_type(8))) unsigned short;
using f32x4 = __attribute__((ext_vector_type(4))) float;
using u32x2 = __attribute__((ext_vector_type(2))) unsigned;
typedef unsigned short ushort;
typedef unsigned int u32;

// LPT order: longest segments first (static; assumes worst-case seg lengths)
__constant__ unsigned char SEG_ORDER[48] = {
    17,0,1,16,44,46,47,15,40,42,43,45,14,36,38,39,41,13,32,34,35,37,
    12,28,30,31,33,11,24,26,27,29,10,20,22,23,25,9,18,19,21,8,7,6,5,4,3,2};

__device__ inline f32x4 mfma16(s16x8 a, s16x8 b, f32x4 c) {
    return __builtin_amdgcn_mfma_f32_16x16x32_bf16(a, b, c, 0, 0, 0);
}

__device__ inline ushort f2bf(float f) {
    unsigned u = __builtin_bit_cast(unsigned, f);
    u += 0x7fffu + ((u >> 16) & 1u);          // RNE
    return (ushort)(u >> 16);
}

__device__ inline u32 cvtpk_bf16(float lo, float hi) {
    u32 r;
    asm("v_cvt_pk_bf16_f32 %0, %1, %2" : "=v"(r) : "v"(lo), "v"(hi));
    return r;
}

__device__ inline float fexp2(float x) {
#if __has_builtin(__builtin_amdgcn_exp2f)
    return __builtin_amdgcn_exp2f(x);
#else
    return exp2f(x);
#endif
}

__device__ inline void gload_lds16(const void* g, void* l) {
    __builtin_amdgcn_global_load_lds(
        (const __attribute__((address_space(1))) u32*)g,
        (__attribute__((address_space(3))) u32*)l,
        16, 0, 0);
}

// ---------------------------------------------------------------------------
// fp32 -> bf16 converters
// ---------------------------------------------------------------------------
__global__ __launch_bounds__(256)
void cvt3_kernel(const float* __restrict__ a, const float* __restrict__ b,
                 const float* __restrict__ c,
                 ushort* __restrict__ ao, ushort* __restrict__ bo2, ushort* __restrict__ co)
{
    const float* src = (blockIdx.y == 0) ? a : (blockIdx.y == 1) ? b : c;
    ushort* dst      = (blockIdx.y == 0) ? ao : (blockIdx.y == 1) ? bo2 : co;
    const size_t i = ((size_t)blockIdx.x * 256 + threadIdx.x) * 8;
    float4 x = *reinterpret_cast<const float4*>(&src[i]);
    float4 y = *reinterpret_cast<const float4*>(&src[i + 4]);
    u16x8 o;
    o[0]=f2bf(x.x); o[1]=f2bf(x.y); o[2]=f2bf(x.z); o[3]=f2bf(x.w);
    o[4]=f2bf(y.x); o[5]=f2bf(y.y); o[6]=f2bf(y.z); o[7]=f2bf(y.w);
    *reinterpret_cast<u16x8*>(&dst[i]) = o;
}

__global__ __launch_bounds__(256)
void cvt4_kernel(const float* __restrict__ a, const float* __restrict__ b,
                 const float* __restrict__ c, const float* __restrict__ d,
                 ushort* __restrict__ ao, ushort* __restrict__ bo2,
                 ushort* __restrict__ co, ushort* __restrict__ dd)
{
    const float* src = (blockIdx.y == 0) ? a : (blockIdx.y == 1) ? b : (blockIdx.y == 2) ? c : d;
    ushort* dst      = (blockIdx.y == 0) ? ao : (blockIdx.y == 1) ? bo2 : (blockIdx.y == 2) ? co : dd;
    const size_t i = ((size_t)blockIdx.x * 256 + threadIdx.x) * 8;
    float4 x = *reinterpret_cast<const float4*>(&src[i]);
    float4 y = *reinterpret_cast<const float4*>(&src[i + 4]);
    u16x8 o;
    o[0]=f2bf(x.x); o[1]=f2bf(x.y); o[2]=f2bf(x.z); o[3]=f2bf(x.w);
    o[4]=f2bf(y.x); o[5]=f2bf(y.y); o[6]=f2bf(y.z); o[7]=f2bf(y.w);
    *reinterpret_cast<u16x8*>(&dst[i]) = o;
}

// ---------------------------------------------------------------------------
// MFMA GEMM core, 128x128 tile, 2-phase double-buffered prefetch:
// STAGE next K-tile BEFORE ds_read+MFMA of current, ONE barrier per K-step
// (vmcnt drain at the barrier lands after ~600cy of compute).
// ---------------------------------------------------------------------------
__device__ inline void mm_core2(const ushort* __restrict__ A, const ushort* __restrict__ W,
                                ushort* Albuf, ushort* Blbuf, int r0, int n0,
                                f32x4 (&acc)[4][4])
{
    const int t  = threadIdx.x;
    const int w  = t >> 6, l = t & 63;
    const int lr = l & 15, lg = l >> 4;
    const int wr = w >> 1, wc = w & 1;
    const int srow = t >> 3;
    const int gch  = (t & 7) ^ (srow & 7);

    auto STAGE = [&](int buf, int kt) {
        #pragma unroll
        for (int c = 0; c < 4; ++c) {
            gload_lds16(&A[(size_t)(r0 + c * 32 + srow) * K + kt + gch * 8],
                        (char*)Albuf + buf * 16384 + c * 4096 + t * 16);
            gload_lds16(&W[(size_t)(n0 + c * 32 + srow) * K + kt + gch * 8],
                        (char*)Blbuf + buf * 16384 + c * 4096 + t * 16);
        }
    };

    STAGE(0, 0);
    __syncthreads();
    int cur = 0;

    for (int kt = 0; kt < K; kt += 64) {
        if (kt + 64 < K) STAGE(cur ^ 1, kt + 64);
        const char* Ab = (const char*)Albuf + cur * 16384;
        const char* Bb = (const char*)Blbuf + cur * 16384;

        #pragma unroll
        for (int ks = 0; ks < 2; ++ks) {
            s16x8 af[4], bf[4];
            #pragma unroll
            for (int mf = 0; mf < 4; ++mf) {
                const int row = wr * 64 + mf * 16 + lr;
                const int ch  = (ks * 4 + lg) ^ (row & 7);
                af[mf] = *reinterpret_cast<const s16x8*>(Ab + row * 128 + ch * 16);
            }
            #pragma unroll
            for (int nf = 0; nf < 4; ++nf) {
                const int row = wc * 64 + nf * 16 + lr;
                const int ch  = (ks * 4 + lg) ^ (row & 7);
                bf[nf] = *reinterpret_cast<const s16x8*>(Bb + row * 128 + ch * 16);
            }
            #pragma unroll
            for (int mf = 0; mf < 4; ++mf)
                #pragma unroll
                for (int nf = 0; nf < 4; ++nf)
                    acc[mf][nf] = mfma16(af[mf], bf[nf], acc[mf][nf]);
        }
        __syncthreads();
        cur ^= 1;
    }
}

__global__ __launch_bounds__(256)
void proj_gemm(const ushort* __restrict__ qa, const ushort* __restrict__ ka,
               const ushort* __restrict__ va,
               const ushort* __restrict__ wq, const ushort* __restrict__ wk,
               const ushort* __restrict__ wv,
               const float* __restrict__ bq, const float* __restrict__ bk,
               const float* __restrict__ bv,
               ushort* __restrict__ qd, ushort* __restrict__ kd, ushort* __restrict__ vtd)
{
    __shared__ ushort Albuf[2 * 128 * 64];
    __shared__ ushort Blbuf[2 * 128 * 64];
    const int z = blockIdx.z;
    const ushort* A    = (z == 0) ? qa : (z == 1) ? ka : va;
    const ushort* W    = (z == 0) ? wq : (z == 1) ? wk : wv;
    const float*  bias = (z == 0) ? bq : (z == 1) ? bk : bv;
    const int r0 = blockIdx.x * 128, n0 = blockIdx.y * 128;

    f32x4 acc[4][4] = {};
    mm_core2(A, W, Albuf, Blbuf, r0, n0, acc);

    const int t = threadIdx.x, w = t >> 6, l = t & 63, lr = l & 15, lg = l >> 4;
    const int wr = w >> 1, wc = w & 1;
    #pragma unroll
    for (int mf = 0; mf < 4; ++mf) {
        #pragma unroll
        for (int nf = 0; nf < 4; ++nf) {
            const int n = n0 + wc * 64 + nf * 16 + lr;
            const int h = n >> 6, e = n & 63;
            const float bb = bias[n];
            #pragma unroll
            for (int rg = 0; rg < 4; ++rg) {
                const int r = r0 + wr * 64 + mf * 16 + lg * 4 + rg;
                const int i = r >> 1, m = r & 1;
                const ushort val = f2bf(acc[mf][nf][rg] + bb);
                if (z < 2) {
                    ushort* dst = (z == 0) ? qd : kd;
                    dst[(((size_t)(h * B + m)) * S + i) * E + e] = val;
                } else {
                    vtd[(((size_t)(h * B + m)) * E + e) * S + i] = val;
                }
            }
        }
    }
}

__global__ __launch_bounds__(256)
void out_gemm(const ushort* __restrict__ A, const ushort* __restrict__ W,
              const float* __restrict__ bias, float* __restrict__ Cout)
{
    __shared__ ushort Albuf[2 * 128 * 64];
    __shared__ ushort Blbuf[2 * 128 * 64];
    const int r0 = blockIdx.x * 128, n0 = blockIdx.y * 128;

    f32x4 acc[4][4] = {};
    mm_core2(A, W, Albuf, Blbuf, r0, n0, acc);

    const int t = threadIdx.x, w = t >> 6, l = t & 63, lr = l & 15, lg = l >> 4;
    const int wr = w >> 1, wc = w & 1;
    #pragma unroll
    for (int mf = 0; mf < 4; ++mf) {
        #pragma unroll
        for (int nf = 0; nf < 4; ++nf) {
            const int n = n0 + wc * 64 + nf * 16 + lr;
            const float bb = bias[n];
            #pragma unroll
            for (int rg = 0; rg < 4; ++rg) {
                const int r = r0 + wr * 64 + mf * 16 + lg * 4 + rg;
                Cout[(size_t)r * D + n] = acc[mf][nf][rg] + bb;
            }
        }
    }
}

// ---------------------------------------------------------------------------
// prescan: fu[m] = min{j : key_mask[j,m]==0} (else S); kmf = mask * KMB2
// ---------------------------------------------------------------------------
__global__ __launch_bounds__(256)
void prescan_kernel(const int* __restrict__ km, int* __restrict__ fu,
                    float* __restrict__ kmf)
{
    __shared__ int red[256];
    const int m = blockIdx.x, t = threadIdx.x;
    int best = S;
    for (int j = t; j < S; j += 256) {
        const int v = km[(size_t)j * B + m];
        kmf[(size_t)m * S + j] = v ? KMB2 : 0.0f;
        if (v == 0) best = min(best, j);
    }
    red[t] = best;
    __syncthreads();
    for (int s = 128; s > 0; s >>= 1) {
        if (t < s) red[t] = min(red[t], red[t + s]);
        __syncthreads();
    }
    if (t == 0) fu[m] = red[0];
}

__device__ inline int nseg_of(int t)  { return (t == 0 || t >= 17) ? 2 : 1; }
__device__ inline int segoff_of(int t){ return (t == 0) ? 0 : (t <= 16 ? t + 1 : 2 * t - 16); }

// ---------------------------------------------------------------------------
// Balanced MFMA flash attention (exp2 domain), swapped QK^T, 2-phase prefetch.
// Softmax slimming: fma-mask, cvt_pk_bf16 P-pack, ds_write_b64, defer-rescale.
// ---------------------------------------------------------------------------
__global__ __launch_bounds__(256)
void attn_seg(const ushort* __restrict__ q, const ushort* __restrict__ k,
              const ushort* __restrict__ vt, const int* __restrict__ fu,
              const float* __restrict__ kmf,
              float* __restrict__ part_O, float* __restrict__ part_ml)
{
    const int s = SEG_ORDER[blockIdx.x];
    const int m = blockIdx.y, h = blockIdx.z;
    int t, kk;
    if (s < 2)       { t = 0;               kk = s; }
    else if (s < 18) { t = s - 1;           kk = 0; }
    else             { t = 17 + ((s - 18) >> 1); kk = (s - 18) & 1; }
    const int i0 = t * 64;
    const int hm = h * B + m;
    const int seg = hm * SEGS_PER_HM + s;

    const int ns = nseg_of(t);
    const int h1 = (t == 0) ? 16 : ((t + 2) >> 1);
    const int jendT = (fu[m] <= i0) ? (t + 1) : 32;   // unmasked key in prefix -> causal skip exact
    const int lo = (ns == 2 && kk == 1) ? h1 : 0;
    const int hi = (ns == 2 && kk == 0) ? min(h1, jendT) : jendT;

    const ushort* Qb  = q  + (size_t)hm * S * E;
    const ushort* Kb  = k  + (size_t)hm * S * E;
    const ushort* Vtb = vt + (size_t)hm * E * S;
    const float*  kmfm = kmf + (size_t)m * S;

    __shared__ ushort Ks[2][KVB * 64];   // [key][e], 128B rows, XOR-chunk swizzled
    __shared__ ushort Vts[2][E * 64];    // [e][key]
    __shared__ ushort Pw[4][16 * 64];    // per-wave P[q][k], 128B rows, swizzled

    const int tid = threadIdx.x;
    const int wv  = tid >> 6;
    const int l   = tid & 63;
    const int lg  = l >> 4;
    const int lcc = l & 15;
    const int a7  = lcc & 7;
    const int gi  = i0 + wv * 16 + lcc;

    const int srow = tid >> 3;
    const int sch  = (tid & 7) ^ (srow & 7);

    s16x8 qf0, qf1;
    {
        const ushort* qp = &Qb[(size_t)gi * E + lg * 8];
        qf0 = *reinterpret_cast<const s16x8*>(qp);
        qf1 = *reinterpret_cast<const s16x8*>(qp + 32);
    }

    float m_run = -INFINITY, l_run = 0.0f;
    f32x4 oacc[4] = {};

    auto STAGE = [&](int buf, int tj) {
        const int j0 = tj * 64;
        gload_lds16(&Kb[(size_t)(j0 + srow) * E + sch * 8],
                    (char*)&Ks[buf][0] + tid * 16);
        gload_lds16(&Kb[(size_t)(j0 + 32 + srow) * E + sch * 8],
                    (char*)&Ks[buf][0] + 4096 + tid * 16);
        gload_lds16(&Vtb[(size_t)srow * S + j0 + sch * 8],
                    (char*)&Vts[buf][0] + tid * 16);
        gload_lds16(&Vtb[(size_t)(32 + srow) * S + j0 + sch * 8],
                    (char*)&Vts[buf][0] + 4096 + tid * 16);
    };

    STAGE(0, lo);
    __syncthreads();
    int cur = 0;

    for (int tj = lo; tj < hi; ++tj) {
        const int j0 = tj * 64;
        if (tj + 1 < hi) STAGE(cur ^ 1, tj + 1);

        float4 km4[4];
        #pragma unroll
        for (int jt = 0; jt < 4; ++jt)
            km4[jt] = *reinterpret_cast<const float4*>(&kmfm[j0 + jt * 16 + lg * 4]);

        // ---- S^T = K . Q^T
        f32x4 sacc[4];
        #pragma unroll
        for (int jt = 0; jt < 4; ++jt) {
            const char* kb = (const char*)&Ks[cur][0] + (jt * 16 + lcc) * 128;
            s16x8 kf0 = *reinterpret_cast<const s16x8*>(kb + (lg ^ a7) * 16);
            s16x8 kf1 = *reinterpret_cast<const s16x8*>(kb + ((lg ^ a7) ^ 4) * 16);
            f32x4 a = {};
            a = mfma16(kf0, qf0, a);
            a = mfma16(kf1, qf1, a);
            sacc[jt] = a;
        }

        // ---- scale + masks in exp2 domain: one fma (+ causal on diagonal tile)
        if (j0 >= i0) {
            #pragma unroll
            for (int jt = 0; jt < 4; ++jt) {
                const int jmi = j0 + jt * 16 + lg * 4 - gi;
                #pragma unroll
                for (int r = 0; r < 4; ++r) {
                    float sc = fmaf(sacc[jt][r], QSCL, -((const float*)&km4[jt])[r]);
                    sc -= (jmi + r > 0) ? KMB2 : 0.0f;
                    sacc[jt][r] = sc;
                }
            }
        } else {
            #pragma unroll
            for (int jt = 0; jt < 4; ++jt)
                #pragma unroll
                for (int r = 0; r < 4; ++r)
                    sacc[jt][r] = fmaf(sacc[jt][r], QSCL, -((const float*)&km4[jt])[r]);
        }

        // ---- online softmax (exp2 domain), defer-rescale when max doesn't grow
        float mm = -INFINITY;
        #pragma unroll
        for (int jt = 0; jt < 4; ++jt)
            #pragma unroll
            for (int r = 0; r < 4; ++r) mm = fmaxf(mm, sacc[jt][r]);
        mm = fmaxf(mm, __shfl_xor(mm, 16));
        mm = fmaxf(mm, __shfl_xor(mm, 32));

        if (!__all(mm <= m_run)) {
            const float m_new = fmaxf(m_run, mm);
            const float scale = fexp2(m_run - m_new);
            m_run = m_new;
            l_run *= scale;
            float scr[4];
            #pragma unroll
            for (int r = 0; r < 4; ++r)
                scr[r] = __shfl(scale, (l & 48) | (lg * 4 + r));
            #pragma unroll
            for (int et = 0; et < 4; ++et)
                #pragma unroll
                for (int r = 0; r < 4; ++r) oacc[et][r] *= scr[r];
        }

        float psum = 0.0f;
        #pragma unroll
        for (int jt = 0; jt < 4; ++jt) {
            const float p0 = fexp2(sacc[jt][0] - m_run);
            const float p1 = fexp2(sacc[jt][1] - m_run);
            const float p2 = fexp2(sacc[jt][2] - m_run);
            const float p3 = fexp2(sacc[jt][3] - m_run);
            psum += (p0 + p1) + (p2 + p3);
            const u32 w0 = cvtpk_bf16(p0, p1);
            const u32 w1 = cvtpk_bf16(p2, p3);
            const int pby = lcc * 128 + (((jt * 2 + (lg >> 1)) ^ a7) << 4) + ((lg & 1) << 3);
            *reinterpret_cast<u32x2*>((char*)&Pw[wv][0] + pby) = (u32x2){w0, w1};
        }
        psum += __shfl_xor(psum, 16);
        psum += __shfl_xor(psum, 32);
        l_run += psum;

        // ---- PV: A = P (per-wave LDS), B = V^T
        {
            const char* pb = (const char*)&Pw[wv][0] + lcc * 128;
            s16x8 pf0 = *reinterpret_cast<const s16x8*>(pb + (lg ^ a7) * 16);
            s16x8 pf1 = *reinterpret_cast<const s16x8*>(pb + ((lg ^ a7) ^ 4) * 16);
            #pragma unroll
            for (int et = 0; et < 4; ++et) {
                const char* vb = (const char*)&Vts[cur][0] + (et * 16 + lcc) * 128;
                s16x8 vf0 = *reinterpret_cast<const s16x8*>(vb + (lg ^ a7) * 16);
                s16x8 vf1 = *reinterpret_cast<const s16x8*>(vb + ((lg ^ a7) ^ 4) * 16);
                oacc[et] = mfma16(pf0, vf0, oacc[et]);
                oacc[et] = mfma16(pf1, vf1, oacc[et]);
            }
        }

        __syncthreads();
        cur ^= 1;
    }

    #pragma unroll
    for (int et = 0; et < 4; ++et)
        #pragma unroll
        for (int r = 0; r < 4; ++r)
            part_O[((size_t)seg * 64 + wv * 16 + lg * 4 + r) * 64 + et * 16 + lcc] = oacc[et][r];
    if (lg == 0) {
        part_ml[((size_t)seg * 64 + wv * 16 + lcc) * 2]     = m_run;
        part_ml[((size_t)seg * 64 + wv * 16 + lcc) * 2 + 1] = l_run;
    }
}

// ---------------------------------------------------------------------------
// combine (exp2 domain): merge 1-2 segments, normalize, emit bf16 [r][n]
// ---------------------------------------------------------------------------
__global__ __launch_bounds__(256)
void attn_combine(const float* __restrict__ part_O, const float* __restrict__ part_ml,
                  ushort* __restrict__ a_ws)
{
    const int t = blockIdx.x, m = blockIdx.y, h = blockIdx.z;
    const int hm = h * B + m;
    const int ns = nseg_of(t);
    const int seg0 = hm * SEGS_PER_HM + segoff_of(t);

    const int tid = threadIdx.x;
    const int row = tid >> 2;
    const int e0  = (tid & 3) * 16;
    const int gi  = t * 64 + row;

    const size_t r0 = (size_t)seg0 * 64 + row;
    const float m0 = part_ml[r0 * 2], l0 = part_ml[r0 * 2 + 1];
    float w0, w1 = 0.0f, linv;
    size_t r1 = 0;
    if (ns == 2) {
        r1 = ((size_t)(seg0 + 1)) * 64 + row;
        const float m1 = part_ml[r1 * 2], l1 = part_ml[r1 * 2 + 1];
        const float ms = fmaxf(m0, m1);
        w0 = fexp2(m0 - ms);
        w1 = fexp2(m1 - ms);
        linv = 1.0f / (l0 * w0 + l1 * w1);
    } else {
        w0 = 1.0f;
        linv = 1.0f / l0;
    }

    ushort* dst = a_ws + ((size_t)gi * B + m) * D + h * E + e0;
    #pragma unroll
    for (int c = 0; c < 4; ++c) {
        float4 o0 = *reinterpret_cast<const float4*>(&part_O[r0 * 64 + e0 + c * 4]);
        float ov[4] = {o0.x, o0.y, o0.z, o0.w};
        if (ns == 2) {
            float4 o1 = *reinterpret_cast<const float4*>(&part_O[r1 * 64 + e0 + c * 4]);
            ov[0] = ov[0] * w0 + o1.x * w1;
            ov[1] = ov[1] * w0 + o1.y * w1;
            ov[2] = ov[2] * w0 + o1.z * w1;
            ov[3] = ov[3] * w0 + o1.w * w1;
        } else {
            ov[0] *= w0; ov[1] *= w0; ov[2] *= w0; ov[3] *= w0;
        }
        dst[c * 4 + 0] = f2bf(ov[0] * linv);
        dst[c * 4 + 1] = f2bf(ov[1] * linv);
        dst[c * 4 + 2] = f2bf(ov[2] * linv);
        dst[c * 4 + 3] = f2bf(ov[3] * linv);
    }
}

} // anonymous namespace

extern "C" void kernel_launch(void* const* d_in, const int* in_sizes, int n_in,
                              void* d_out, int out_size, void* d_ws, size_t ws_size,
                              hipStream_t stream)
{
    const float* query = (const float*)d_in[0];
    const float* key   = (const float*)d_in[1];
    const float* value = (const float*)d_in[2];
    const int*   kmask = (const int*)  d_in[3];
    const float* Wq    = (const float*)d_in[4];
    const float* bq    = (const float*)d_in[5];
    const float* Wk    = (const float*)d_in[6];
    const float* bk    = (const float*)d_in[7];
    const float* Wv    = (const float*)d_in[8];
    const float* bv    = (const float*)d_in[9];
    const float* Wo    = (const float*)d_in[10];
    const float* bo    = (const float*)d_in[11];
    float* out = (float*)d_out;

    const size_t act = (size_t)RM * D;
    const size_t wsz = (size_t)D * D;
    ushort* wob  = (ushort*)d_ws;
    ushort* wqb  = wob + wsz;
    ushort* wkb  = wqb + wsz;
    ushort* wvb  = wkb + wsz;
    ushort* qa   = wvb + wsz;
    ushort* ka   = qa + act;
    ushort* va   = ka + act;
    ushort* q_ws = va + act;
    ushort* k_ws = q_ws + act;
    ushort* vt_ws= k_ws + act;
    ushort* a_ws = vt_ws + act;
    float* part_O  = (float*)qa;
    float* part_ml = (float*)wqb;
    int*   fu      = (int*)wkb;
    float* kmf     = (float*)wkb + 8;

    cvt3_kernel<<<dim3(act / 8 / 256, 3), 256, 0, stream>>>(query, key, value, qa, ka, va);
    cvt4_kernel<<<dim3(wsz / 8 / 256, 4), 256, 0, stream>>>(Wq, Wk, Wv, Wo, wqb, wkb, wvb, wob);

    proj_gemm<<<dim3(RM / 128, D / 128, 3), 256, 0, stream>>>(
        qa, ka, va, wqb, wkb, wvb, bq, bk, bv, q_ws, k_ws, vt_ws);

    prescan_kernel<<<dim3(B), 256, 0, stream>>>(kmask, fu, kmf);

    attn_seg<<<dim3(SEGS_PER_HM, B, H), 256, 0, stream>>>(
        q_ws, k_ws, vt_ws, fu, kmf, part_O, part_ml);

    attn_combine<<<dim3(S / 64, B, H), 256, 0, stream>>>(part_O, part_ml, a_ws);

    out_gemm<<<dim3(RM / 128, D / 128), 256, 0, stream>>>(a_ws, wob, bo, out);
}

// Round 9
// 148.360 us; speedup vs baseline: 10.9891x; 1.0204x over previous
//
#include <hip/hip_runtime.h>
#include <cmath>

namespace {

constexpr int S = 2048, B = 2, D = 1024, H = 16, E = 64;
constexpr int RM = S * B;
constexpr int K = D;
constexpr int KVB = 64;
constexpr int SEGS_PER_HM = 48;   // t=0:2 segs, t=1..16:1, t=17..31:2

// exp2-domain constants: score2 = raw*(0.125*log2e) - km*KMB2 - causal*KMB2
constexpr float QSCL = 0.18033688011112043f;      // 0.125 * log2(e)
constexpr float KMB2 = 1.4426950408889634e18f;    // 1e18 * log2(e)

using s16x8 = __attribute__((ext_vector_type(8))) short;
using u16x8 = __attribute__((ext_vector_type(8))) unsigned short;
using f32x4 = __attribute__((ext_vector_type(4))) float;
using u32x2 = __attribute__((ext_vector_type(2))) unsigned;
typedef unsigned short ushort;
typedef unsigned int u32;

// LPT order: longest segments first (static; assumes worst-case seg lengths)
__constant__ unsigned char SEG_ORDER[48] = {
    17,0,1,16,44,46,47,15,40,42,43,45,14,36,38,39,41,13,32,34,35,37,
    12,28,30,31,33,11,24,26,27,29,10,20,22,23,25,9,18,19,21,8,7,6,5,4,3,2};

__device__ inline f32x4 mfma16(s16x8 a, s16x8 b, f32x4 c) {
    return __builtin_amdgcn_mfma_f32_16x16x32_bf16(a, b, c, 0, 0, 0);
}

__device__ inline ushort f2bf(float f) {
    unsigned u = __builtin_bit_cast(unsigned, f);
    u += 0x7fffu + ((u >> 16) & 1u);          // RNE
    return (ushort)(u >> 16);
}

__device__ inline u32 cvtpk_bf16(float lo, float hi) {
    u32 r;
    asm("v_cvt_pk_bf16_f32 %0, %1, %2" : "=v"(r) : "v"(lo), "v"(hi));
    return r;
}

__device__ inline float fexp2(float x) {
#if __has_builtin(__builtin_amdgcn_exp2f)
    return __builtin_amdgcn_exp2f(x);
#else
    return exp2f(x);
#endif
}

__device__ inline void gload_lds16(const void* g, void* l) {
    __builtin_amdgcn_global_load_lds(
        (const __attribute__((address_space(1))) u32*)g,
        (__attribute__((address_space(3))) u32*)l,
        16, 0, 0);
}

// ---------------------------------------------------------------------------
// fp32 -> bf16 converters
// ---------------------------------------------------------------------------
__global__ __launch_bounds__(256)
void cvt3_kernel(const float* __restrict__ a, const float* __restrict__ b,
                 const float* __restrict__ c,
                 ushort* __restrict__ ao, ushort* __restrict__ bo2, ushort* __restrict__ co)
{
    const float* src = (blockIdx.y == 0) ? a : (blockIdx.y == 1) ? b : c;
    ushort* dst      = (blockIdx.y == 0) ? ao : (blockIdx.y == 1) ? bo2 : co;
    const size_t i = ((size_t)blockIdx.x * 256 + threadIdx.x) * 8;
    float4 x = *reinterpret_cast<const float4*>(&src[i]);
    float4 y = *reinterpret_cast<const float4*>(&src[i + 4]);
    u16x8 o;
    o[0]=f2bf(x.x); o[1]=f2bf(x.y); o[2]=f2bf(x.z); o[3]=f2bf(x.w);
    o[4]=f2bf(y.x); o[5]=f2bf(y.y); o[6]=f2bf(y.z); o[7]=f2bf(y.w);
    *reinterpret_cast<u16x8*>(&dst[i]) = o;
}

__global__ __launch_bounds__(256)
void cvt4_kernel(const float* __restrict__ a, const float* __restrict__ b,
                 const float* __restrict__ c, const float* __restrict__ d,
                 ushort* __restrict__ ao, ushort* __restrict__ bo2,
                 ushort* __restrict__ co, ushort* __restrict__ dd)
{
    const float* src = (blockIdx.y == 0) ? a : (blockIdx.y == 1) ? b : (blockIdx.y == 2) ? c : d;
    ushort* dst      = (blockIdx.y == 0) ? ao : (blockIdx.y == 1) ? bo2 : (blockIdx.y == 2) ? co : dd;
    const size_t i = ((size_t)blockIdx.x * 256 + threadIdx.x) * 8;
    float4 x = *reinterpret_cast<const float4*>(&src[i]);
    float4 y = *reinterpret_cast<const float4*>(&src[i + 4]);
    u16x8 o;
    o[0]=f2bf(x.x); o[1]=f2bf(x.y); o[2]=f2bf(x.z); o[3]=f2bf(x.w);
    o[4]=f2bf(y.x); o[5]=f2bf(y.y); o[6]=f2bf(y.z); o[7]=f2bf(y.w);
    *reinterpret_cast<u16x8*>(&dst[i]) = o;
}

// ---------------------------------------------------------------------------
// MFMA GEMM core, 128x128 tile, 8 waves (512 thr), 2-phase dbuf prefetch.
// Wave quadrants: 2x4 grid of 64x32 (acc 4x2). Linear LDS + XOR chunk swizzle
// with pre-swizzled global source (rule #21). ONLY change vs R7: wave count.
// ---------------------------------------------------------------------------
__device__ inline void mm_core2(const ushort* __restrict__ A, const ushort* __restrict__ W,
                                ushort* Albuf, ushort* Blbuf, int r0, int n0,
                                f32x4 (&acc)[4][2])
{
    const int t  = threadIdx.x;
    const int w  = t >> 6, l = t & 63;
    const int lr = l & 15, lg = l >> 4;
    const int wr = w >> 2, wc = w & 3;       // 2x4 grid of 64x32 quadrants
    const int srow = t >> 3;                 // 0..63
    const int gch  = (t & 7) ^ (srow & 7);

    auto STAGE = [&](int buf, int kt) {
        #pragma unroll
        for (int c = 0; c < 2; ++c) {
            gload_lds16(&A[(size_t)(r0 + c * 64 + srow) * K + kt + gch * 8],
                        (char*)Albuf + buf * 16384 + c * 8192 + t * 16);
            gload_lds16(&W[(size_t)(n0 + c * 64 + srow) * K + kt + gch * 8],
                        (char*)Blbuf + buf * 16384 + c * 8192 + t * 16);
        }
    };

    STAGE(0, 0);
    __syncthreads();
    int cur = 0;

    for (int kt = 0; kt < K; kt += 64) {
        if (kt + 64 < K) STAGE(cur ^ 1, kt + 64);
        const char* Ab = (const char*)Albuf + cur * 16384;
        const char* Bb = (const char*)Blbuf + cur * 16384;

        #pragma unroll
        for (int ks = 0; ks < 2; ++ks) {
            s16x8 af[4], bf[2];
            #pragma unroll
            for (int mf = 0; mf < 4; ++mf) {
                const int row = wr * 64 + mf * 16 + lr;
                const int ch  = (ks * 4 + lg) ^ (row & 7);
                af[mf] = *reinterpret_cast<const s16x8*>(Ab + row * 128 + ch * 16);
            }
            #pragma unroll
            for (int nf = 0; nf < 2; ++nf) {
                const int row = wc * 32 + nf * 16 + lr;
                const int ch  = (ks * 4 + lg) ^ (row & 7);
                bf[nf] = *reinterpret_cast<const s16x8*>(Bb + row * 128 + ch * 16);
            }
            #pragma unroll
            for (int mf = 0; mf < 4; ++mf)
                #pragma unroll
                for (int nf = 0; nf < 2; ++nf)
                    acc[mf][nf] = mfma16(af[mf], bf[nf], acc[mf][nf]);
        }
        __syncthreads();
        cur ^= 1;
    }
}

__global__ __launch_bounds__(512)
void proj_gemm(const ushort* __restrict__ qa, const ushort* __restrict__ ka,
               const ushort* __restrict__ va,
               const ushort* __restrict__ wq, const ushort* __restrict__ wk,
               const ushort* __restrict__ wv,
               const float* __restrict__ bq, const float* __restrict__ bk,
               const float* __restrict__ bv,
               ushort* __restrict__ qd, ushort* __restrict__ kd, ushort* __restrict__ vtd)
{
    __shared__ ushort Albuf[2 * 128 * 64];
    __shared__ ushort Blbuf[2 * 128 * 64];
    const int z = blockIdx.z;
    const ushort* A    = (z == 0) ? qa : (z == 1) ? ka : va;
    const ushort* W    = (z == 0) ? wq : (z == 1) ? wk : wv;
    const float*  bias = (z == 0) ? bq : (z == 1) ? bk : bv;
    const int r0 = blockIdx.x * 128, n0 = blockIdx.y * 128;

    f32x4 acc[4][2] = {};
    mm_core2(A, W, Albuf, Blbuf, r0, n0, acc);

    const int t = threadIdx.x, w = t >> 6, l = t & 63, lr = l & 15, lg = l >> 4;
    const int wr = w >> 2, wc = w & 3;
    #pragma unroll
    for (int mf = 0; mf < 4; ++mf) {
        #pragma unroll
        for (int nf = 0; nf < 2; ++nf) {
            const int n = n0 + wc * 32 + nf * 16 + lr;
            const int h = n >> 6, e = n & 63;
            const float bb = bias[n];
            #pragma unroll
            for (int rg = 0; rg < 4; ++rg) {
                const int r = r0 + wr * 64 + mf * 16 + lg * 4 + rg;
                const int i = r >> 1, m = r & 1;
                const ushort val = f2bf(acc[mf][nf][rg] + bb);
                if (z < 2) {
                    ushort* dst = (z == 0) ? qd : kd;
                    dst[(((size_t)(h * B + m)) * S + i) * E + e] = val;
                } else {
                    vtd[(((size_t)(h * B + m)) * E + e) * S + i] = val;
                }
            }
        }
    }
}

__global__ __launch_bounds__(512)
void out_gemm(const ushort* __restrict__ A, const ushort* __restrict__ W,
              const float* __restrict__ bias, float* __restrict__ Cout)
{
    __shared__ ushort Albuf[2 * 128 * 64];
    __shared__ ushort Blbuf[2 * 128 * 64];
    const int r0 = blockIdx.x * 128, n0 = blockIdx.y * 128;

    f32x4 acc[4][2] = {};
    mm_core2(A, W, Albuf, Blbuf, r0, n0, acc);

    const int t = threadIdx.x, w = t >> 6, l = t & 63, lr = l & 15, lg = l >> 4;
    const int wr = w >> 2, wc = w & 3;
    #pragma unroll
    for (int mf = 0; mf < 4; ++mf) {
        #pragma unroll
        for (int nf = 0; nf < 2; ++nf) {
            const int n = n0 + wc * 32 + nf * 16 + lr;
            const float bb = bias[n];
            #pragma unroll
            for (int rg = 0; rg < 4; ++rg) {
                const int r = r0 + wr * 64 + mf * 16 + lg * 4 + rg;
                Cout[(size_t)r * D + n] = acc[mf][nf][rg] + bb;
            }
        }
    }
}

// ---------------------------------------------------------------------------
// prescan: fu[m] = min{j : key_mask[j,m]==0} (else S); kmf = mask * KMB2
// ---------------------------------------------------------------------------
__global__ __launch_bounds__(256)
void prescan_kernel(const int* __restrict__ km, int* __restrict__ fu,
                    float* __restrict__ kmf)
{
    __shared__ int red[256];
    const int m = blockIdx.x, t = threadIdx.x;
    int best = S;
    for (int j = t; j < S; j += 256) {
        const int v = km[(size_t)j * B + m];
        kmf[(size_t)m * S + j] = v ? KMB2 : 0.0f;
        if (v == 0) best = min(best, j);
    }
    red[t] = best;
    __syncthreads();
    for (int s = 128; s > 0; s >>= 1) {
        if (t < s) red[t] = min(red[t], red[t + s]);
        __syncthreads();
    }
    if (t == 0) fu[m] = red[0];
}

__device__ inline int nseg_of(int t)  { return (t == 0 || t >= 17) ? 2 : 1; }
__device__ inline int segoff_of(int t){ return (t == 0) ? 0 : (t <= 16 ? t + 1 : 2 * t - 16); }

// ---------------------------------------------------------------------------
// Balanced MFMA flash attention (exp2 domain), swapped QK^T, 2-phase prefetch.
// BYTE-IDENTICAL to R7 (proven passing).
// ---------------------------------------------------------------------------
__global__ __launch_bounds__(256)
void attn_seg(const ushort* __restrict__ q, const ushort* __restrict__ k,
              const ushort* __restrict__ vt, const int* __restrict__ fu,
              const float* __restrict__ kmf,
              float* __restrict__ part_O, float* __restrict__ part_ml)
{
    const int s = SEG_ORDER[blockIdx.x];
    const int m = blockIdx.y, h = blockIdx.z;
    int t, kk;
    if (s < 2)       { t = 0;               kk = s; }
    else if (s < 18) { t = s - 1;           kk = 0; }
    else             { t = 17 + ((s - 18) >> 1); kk = (s - 18) & 1; }
    const int i0 = t * 64;
    const int hm = h * B + m;
    const int seg = hm * SEGS_PER_HM + s;

    const int ns = nseg_of(t);
    const int h1 = (t == 0) ? 16 : ((t + 2) >> 1);
    const int jendT = (fu[m] <= i0) ? (t + 1) : 32;
    const int lo = (ns == 2 && kk == 1) ? h1 : 0;
    const int hi = (ns == 2 && kk == 0) ? min(h1, jendT) : jendT;

    const ushort* Qb  = q  + (size_t)hm * S * E;
    const ushort* Kb  = k  + (size_t)hm * S * E;
    const ushort* Vtb = vt + (size_t)hm * E * S;
    const float*  kmfm = kmf + (size_t)m * S;

    __shared__ ushort Ks[2][KVB * 64];
    __shared__ ushort Vts[2][E * 64];
    __shared__ ushort Pw[4][16 * 64];

    const int tid = threadIdx.x;
    const int wv  = tid >> 6;
    const int l   = tid & 63;
    const int lg  = l >> 4;
    const int lcc = l & 15;
    const int a7  = lcc & 7;
    const int gi  = i0 + wv * 16 + lcc;

    const int srow = tid >> 3;
    const int sch  = (tid & 7) ^ (srow & 7);

    s16x8 qf0, qf1;
    {
        const ushort* qp = &Qb[(size_t)gi * E + lg * 8];
        qf0 = *reinterpret_cast<const s16x8*>(qp);
        qf1 = *reinterpret_cast<const s16x8*>(qp + 32);
    }

    float m_run = -INFINITY, l_run = 0.0f;
    f32x4 oacc[4] = {};

    auto STAGE = [&](int buf, int tj) {
        const int j0 = tj * 64;
        gload_lds16(&Kb[(size_t)(j0 + srow) * E + sch * 8],
                    (char*)&Ks[buf][0] + tid * 16);
        gload_lds16(&Kb[(size_t)(j0 + 32 + srow) * E + sch * 8],
                    (char*)&Ks[buf][0] + 4096 + tid * 16);
        gload_lds16(&Vtb[(size_t)srow * S + j0 + sch * 8],
                    (char*)&Vts[buf][0] + tid * 16);
        gload_lds16(&Vtb[(size_t)(32 + srow) * S + j0 + sch * 8],
                    (char*)&Vts[buf][0] + 4096 + tid * 16);
    };

    STAGE(0, lo);
    __syncthreads();
    int cur = 0;

    for (int tj = lo; tj < hi; ++tj) {
        const int j0 = tj * 64;
        if (tj + 1 < hi) STAGE(cur ^ 1, tj + 1);

        float4 km4[4];
        #pragma unroll
        for (int jt = 0; jt < 4; ++jt)
            km4[jt] = *reinterpret_cast<const float4*>(&kmfm[j0 + jt * 16 + lg * 4]);

        // ---- S^T = K . Q^T
        f32x4 sacc[4];
        #pragma unroll
        for (int jt = 0; jt < 4; ++jt) {
            const char* kb = (const char*)&Ks[cur][0] + (jt * 16 + lcc) * 128;
            s16x8 kf0 = *reinterpret_cast<const s16x8*>(kb + (lg ^ a7) * 16);
            s16x8 kf1 = *reinterpret_cast<const s16x8*>(kb + ((lg ^ a7) ^ 4) * 16);
            f32x4 a = {};
            a = mfma16(kf0, qf0, a);
            a = mfma16(kf1, qf1, a);
            sacc[jt] = a;
        }

        // ---- scale + masks in exp2 domain
        if (j0 >= i0) {
            #pragma unroll
            for (int jt = 0; jt < 4; ++jt) {
                const int jmi = j0 + jt * 16 + lg * 4 - gi;
                #pragma unroll
                for (int r = 0; r < 4; ++r) {
                    float sc = fmaf(sacc[jt][r], QSCL, -((const float*)&km4[jt])[r]);
                    sc -= (jmi + r > 0) ? KMB2 : 0.0f;
                    sacc[jt][r] = sc;
                }
            }
        } else {
            #pragma unroll
            for (int jt = 0; jt < 4; ++jt)
                #pragma unroll
                for (int r = 0; r < 4; ++r)
                    sacc[jt][r] = fmaf(sacc[jt][r], QSCL, -((const float*)&km4[jt])[r]);
        }

        // ---- online softmax, defer-rescale
        float mm = -INFINITY;
        #pragma unroll
        for (int jt = 0; jt < 4; ++jt)
            #pragma unroll
            for (int r = 0; r < 4; ++r) mm = fmaxf(mm, sacc[jt][r]);
        mm = fmaxf(mm, __shfl_xor(mm, 16));
        mm = fmaxf(mm, __shfl_xor(mm, 32));

        if (!__all(mm <= m_run)) {
            const float m_new = fmaxf(m_run, mm);
            const float scale = fexp2(m_run - m_new);
            m_run = m_new;
            l_run *= scale;
            float scr[4];
            #pragma unroll
            for (int r = 0; r < 4; ++r)
                scr[r] = __shfl(scale, (l & 48) | (lg * 4 + r));
            #pragma unroll
            for (int et = 0; et < 4; ++et)
                #pragma unroll
                for (int r = 0; r < 4; ++r) oacc[et][r] *= scr[r];
        }

        float psum = 0.0f;
        #pragma unroll
        for (int jt = 0; jt < 4; ++jt) {
            const float p0 = fexp2(sacc[jt][0] - m_run);
            const float p1 = fexp2(sacc[jt][1] - m_run);
            const float p2 = fexp2(sacc[jt][2] - m_run);
            const float p3 = fexp2(sacc[jt][3] - m_run);
            psum += (p0 + p1) + (p2 + p3);
            const u32 w0 = cvtpk_bf16(p0, p1);
            const u32 w1 = cvtpk_bf16(p2, p3);
            const int pby = lcc * 128 + (((jt * 2 + (lg >> 1)) ^ a7) << 4) + ((lg & 1) << 3);
            *reinterpret_cast<u32x2*>((char*)&Pw[wv][0] + pby) = (u32x2){w0, w1};
        }
        psum += __shfl_xor(psum, 16);
        psum += __shfl_xor(psum, 32);
        l_run += psum;

        // ---- PV: A = P (per-wave LDS), B = V^T
        {
            const char* pb = (const char*)&Pw[wv][0] + lcc * 128;
            s16x8 pf0 = *reinterpret_cast<const s16x8*>(pb + (lg ^ a7) * 16);
            s16x8 pf1 = *reinterpret_cast<const s16x8*>(pb + ((lg ^ a7) ^ 4) * 16);
            #pragma unroll
            for (int et = 0; et < 4; ++et) {
                const char* vb = (const char*)&Vts[cur][0] + (et * 16 + lcc) * 128;
                s16x8 vf0 = *reinterpret_cast<const s16x8*>(vb + (lg ^ a7) * 16);
                s16x8 vf1 = *reinterpret_cast<const s16x8*>(vb + ((lg ^ a7) ^ 4) * 16);
                oacc[et] = mfma16(pf0, vf0, oacc[et]);
                oacc[et] = mfma16(pf1, vf1, oacc[et]);
            }
        }

        __syncthreads();
        cur ^= 1;
    }

    #pragma unroll
    for (int et = 0; et < 4; ++et)
        #pragma unroll
        for (int r = 0; r < 4; ++r)
            part_O[((size_t)seg * 64 + wv * 16 + lg * 4 + r) * 64 + et * 16 + lcc] = oacc[et][r];
    if (lg == 0) {
        part_ml[((size_t)seg * 64 + wv * 16 + lcc) * 2]     = m_run;
        part_ml[((size_t)seg * 64 + wv * 16 + lcc) * 2 + 1] = l_run;
    }
}

// ---------------------------------------------------------------------------
// combine (exp2 domain): merge 1-2 segments, normalize, emit bf16 [r][n]
// ---------------------------------------------------------------------------
__global__ __launch_bounds__(256)
void attn_combine(const float* __restrict__ part_O, const float* __restrict__ part_ml,
                  ushort* __restrict__ a_ws)
{
    const int t = blockIdx.x, m = blockIdx.y, h = blockIdx.z;
    const int hm = h * B + m;
    const int ns = nseg_of(t);
    const int seg0 = hm * SEGS_PER_HM + segoff_of(t);

    const int tid = threadIdx.x;
    const int row = tid >> 2;
    const int e0  = (tid & 3) * 16;
    const int gi  = t * 64 + row;

    const size_t r0 = (size_t)seg0 * 64 + row;
    const float m0 = part_ml[r0 * 2], l0 = part_ml[r0 * 2 + 1];
    float w0, w1 = 0.0f, linv;
    size_t r1 = 0;
    if (ns == 2) {
        r1 = ((size_t)(seg0 + 1)) * 64 + row;
        const float m1 = part_ml[r1 * 2], l1 = part_ml[r1 * 2 + 1];
        const float ms = fmaxf(m0, m1);
        w0 = fexp2(m0 - ms);
        w1 = fexp2(m1 - ms);
        linv = 1.0f / (l0 * w0 + l1 * w1);
    } else {
        w0 = 1.0f;
        linv = 1.0f / l0;
    }

    ushort* dst = a_ws + ((size_t)gi * B + m) * D + h * E + e0;
    #pragma unroll
    for (int c = 0; c < 4; ++c) {
        float4 o0 = *reinterpret_cast<const float4*>(&part_O[r0 * 64 + e0 + c * 4]);
        float ov[4] = {o0.x, o0.y, o0.z, o0.w};
        if (ns == 2) {
            float4 o1 = *reinterpret_cast<const float4*>(&part_O[r1 * 64 + e0 + c * 4]);
            ov[0] = ov[0] * w0 + o1.x * w1;
            ov[1] = ov[1] * w0 + o1.y * w1;
            ov[2] = ov[2] * w0 + o1.z * w1;
            ov[3] = ov[3] * w0 + o1.w * w1;
        } else {
            ov[0] *= w0; ov[1] *= w0; ov[2] *= w0; ov[3] *= w0;
        }
        dst[c * 4 + 0] = f2bf(ov[0] * linv);
        dst[c * 4 + 1] = f2bf(ov[1] * linv);
        dst[c * 4 + 2] = f2bf(ov[2] * linv);
        dst[c * 4 + 3] = f2bf(ov[3] * linv);
    }
}

} // anonymous namespace

extern "C" void kernel_launch(void* const* d_in, const int* in_sizes, int n_in,
                              void* d_out, int out_size, void* d_ws, size_t ws_size,
                              hipStream_t stream)
{
    const float* query = (const float*)d_in[0];
    const float* key   = (const float*)d_in[1];
    const float* value = (const float*)d_in[2];
    const int*   kmask = (const int*)  d_in[3];
    const float* Wq    = (const float*)d_in[4];
    const float* bq    = (const float*)d_in[5];
    const float* Wk    = (const float*)d_in[6];
    const float* bk    = (const float*)d_in[7];
    const float* Wv    = (const float*)d_in[8];
    const float* bv    = (const float*)d_in[9];
    const float* Wo    = (const float*)d_in[10];
    const float* bo    = (const float*)d_in[11];
    float* out = (float*)d_out;

    const size_t act = (size_t)RM * D;
    const size_t wsz = (size_t)D * D;
    ushort* wob  = (ushort*)d_ws;
    ushort* wqb  = wob + wsz;
    ushort* wkb  = wqb + wsz;
    ushort* wvb  = wkb + wsz;
    ushort* qa   = wvb + wsz;
    ushort* ka   = qa + act;
    ushort* va   = ka + act;
    ushort* q_ws = va + act;
    ushort* k_ws = q_ws + act;
    ushort* vt_ws= k_ws + act;
    ushort* a_ws = vt_ws + act;
    float* part_O  = (float*)qa;           // 1536*64*64 f32 == 3*act ushorts
    float* part_ml = (float*)wqb;          // 786 KB < 2 MB
    int*   fu      = (int*)wkb;            // 16 B
    float* kmf     = (float*)wkb + 8;      // S*B f32 = 16 KB < 2 MB

    cvt3_kernel<<<dim3(act / 8 / 256, 3), 256, 0, stream>>>(query, key, value, qa, ka, va);
    cvt4_kernel<<<dim3(wsz / 8 / 256, 4), 256, 0, stream>>>(Wq, Wk, Wv, Wo, wqb, wkb, wvb, wob);

    proj_gemm<<<dim3(RM / 128, D / 128, 3), 512, 0, stream>>>(
        qa, ka, va, wqb, wkb, wvb, bq, bk, bv, q_ws, k_ws, vt_ws);

    prescan_kernel<<<dim3(B), 256, 0, stream>>>(kmask, fu, kmf);

    attn_seg<<<dim3(SEGS_PER_HM, B, H), 256, 0, stream>>>(
        q_ws, k_ws, vt_ws, fu, kmf, part_O, part_ml);

    attn_combine<<<dim3(S / 64, B, H), 256, 0, stream>>>(part_O, part_ml, a_ws);

    out_gemm<<<dim3(RM / 128, D / 128), 512, 0, stream>>>(a_ws, wob, bo, out);
}